// Round 1
// baseline (4402.298 us; speedup 1.0000x reference)
//
#include <hip/hip_runtime.h>

#define NNODES 100000
#define NEDGES 3200000
#define NPG 200
#define NGRAPH 500
#define FIN 128
#define HID 32
#define KP 50
#define NCLS 10

// ---------------- degree ----------------
__global__ __launch_bounds__(256) void k_deg(const int* __restrict__ src,
                                             const int* __restrict__ dst,
                                             int* __restrict__ deg) {
    int e = blockIdx.x * 256 + threadIdx.x;
    if (e >= NEDGES) return;
    int s = src[e], d = dst[e];
    if (s != d) atomicAdd(&deg[d], 1);
}

__global__ __launch_bounds__(256) void k_dinv(const int* __restrict__ deg,
                                              float* __restrict__ dinv) {
    int n = blockIdx.x * 256 + threadIdx.x;
    if (n >= NNODES) return;
    dinv[n] = 1.0f / sqrtf((float)deg[n] + 1.0f);
}

// ---------------- h = X @ W  (W is K x 32) ----------------
__global__ __launch_bounds__(256) void k_matmul(const float* __restrict__ X, int ldx, int K,
                                                const float* __restrict__ W,
                                                float* __restrict__ h) {
    __shared__ float Wl[FIN * HID];
    int t = threadIdx.x;
    for (int idx = t; idx < K * HID; idx += 256) Wl[idx] = W[idx];
    __syncthreads();
    int n = blockIdx.x * 8 + (t >> 5);
    int j = t & 31;
    const float* xr = X + (size_t)n * ldx;
    float acc = 0.f;
    for (int k = 0; k < K; ++k) acc += xr[k] * Wl[k * HID + j];
    h[n * HID + j] = acc;
}

// ---------------- edge scatter: agg[d] += dinv[s]*dinv[d]*h[s] ----------------
__global__ __launch_bounds__(256) void k_scatter(const int* __restrict__ src,
                                                 const int* __restrict__ dst,
                                                 const float* __restrict__ dinv,
                                                 const float* __restrict__ h,
                                                 float* __restrict__ agg) {
    unsigned t = blockIdx.x * 256 + threadIdx.x;  // e*8 + g
    int e = t >> 3;
    int g = t & 7;
    int s = src[e], d = dst[e];
    if (s == d) return;
    float nrm = dinv[s] * dinv[d];
    float4 hv = *reinterpret_cast<const float4*>(h + (size_t)s * HID + g * 4);
    float* ap = agg + (size_t)d * HID + g * 4;
    atomicAdd(ap + 0, nrm * hv.x);
    atomicAdd(ap + 1, nrm * hv.y);
    atomicAdd(ap + 2, nrm * hv.z);
    atomicAdd(ap + 3, nrm * hv.w);
}

// ---------------- finalize: xc[:, off:off+32] = tanh(agg + h/deg + b) ----------------
__global__ __launch_bounds__(256) void k_finalize(const float* __restrict__ h,
                                                  const float* __restrict__ agg,
                                                  const float* __restrict__ dinv,
                                                  const float* __restrict__ bias,
                                                  float* __restrict__ xc, int coloff) {
    int i = blockIdx.x * 256 + threadIdx.x;  // n*32+f
    if (i >= NNODES * HID) return;
    int n = i >> 5, f = i & 31;
    float di = dinv[n];
    float v = agg[i] + h[i] * (di * di) + bias[f];
    xc[(size_t)n * 96 + coloff + f] = tanhf(v);
}

// ---------------- stable top-50 sort-pool per graph ----------------
__global__ __launch_bounds__(256) void k_sortpool(const float* __restrict__ xc,
                                                  float* __restrict__ pooled) {
    int g = blockIdx.x;
    __shared__ float vals[NPG];
    __shared__ int ranks[NPG];
    int t = threadIdx.x;
    if (t < NPG) vals[t] = xc[((size_t)g * NPG + t) * 96 + 95];
    __syncthreads();
    if (t < NPG) {
        float v = vals[t];
        int r = 0;
        for (int k = 0; k < NPG; ++k) {
            float vk = vals[k];
            r += (vk > v) || (vk == v && k < t);  // desc value, stable by index
        }
        ranks[t] = r;
    }
    __syncthreads();
    for (int j = 0; j < NPG; ++j) {
        int r = ranks[j];
        if (r < KP && t < 96)
            pooled[((size_t)g * KP + r) * 96 + t] = xc[((size_t)g * NPG + j) * 96 + t];
    }
}

// ---------------- capsule-1 priors: block per (o,i), Wc1 slice in LDS ----------------
__global__ __launch_bounds__(256) void k_priors1(const float* __restrict__ pooled,
                                                 const float* __restrict__ Wc1,
                                                 float* __restrict__ priors) {
    int o = blockIdx.x / KP, i = blockIdx.x % KP;
    __shared__ float Wl[32 * 97];   // padded: bank-conflict-free
    __shared__ float ul[8 * 96];
    int t = threadIdx.x;
    const float* wsrc = Wc1 + ((size_t)(o * KP + i) * 32) * 96;
    for (int idx = t; idx < 32 * 96; idx += 256)
        Wl[(idx / 96) * 97 + (idx % 96)] = wsrc[idx];
    int L = t & 31, bs = t >> 5;
    for (int b0 = 0; b0 < NGRAPH; b0 += 8) {
        __syncthreads();
        for (int idx = t; idx < 8 * 96; idx += 256) {
            int bb = idx / 96, l = idx % 96;
            int b = b0 + bb;
            ul[idx] = (b < NGRAPH) ? pooled[((size_t)b * KP + i) * 96 + l] : 0.f;
        }
        __syncthreads();
        int b = b0 + bs;
        if (b < NGRAPH) {
            const float* wr = &Wl[L * 97];
            const float* ur = &ul[bs * 96];
            float acc = 0.f;
            for (int l = 0; l < 96; ++l) acc += wr[l] * ur[l];
            priors[(((size_t)b * 16 + o) * KP + i) * 32 + L] = acc;
        }
    }
}

// ---------------- capsule-1 routing (per graph, all in LDS) ----------------
__global__ __launch_bounds__(256) void k_routing1(const float* __restrict__ priors_g,
                                                  float* __restrict__ v_out) {
    int b = blockIdx.x;
    __shared__ float P[16 * KP * 33];  // [o][i][L] padded 32->33
    __shared__ float logits[16 * KP];
    __shared__ float c[16 * KP];
    __shared__ float s[16 * 32];
    __shared__ float v[16 * 32];
    __shared__ float scale[16];
    int t = threadIdx.x;
    const float* pg = priors_g + (size_t)b * (16 * KP * 32);
    for (int idx = t; idx < 16 * KP * 32; idx += 256)
        P[(idx >> 5) * 33 + (idx & 31)] = pg[idx];
    for (int idx = t; idx < 16 * KP; idx += 256) logits[idx] = 0.f;
    __syncthreads();
    for (int it = 0; it < 3; ++it) {
        if (t < KP) {  // softmax over o for column i=t
            float m = -1e30f;
            for (int o = 0; o < 16; ++o) m = fmaxf(m, logits[o * KP + t]);
            float sum = 0.f;
            for (int o = 0; o < 16; ++o) {
                float e = expf(logits[o * KP + t] - m);
                c[o * KP + t] = e;
                sum += e;
            }
            for (int o = 0; o < 16; ++o) c[o * KP + t] /= sum;
        }
        __syncthreads();
        for (int idx = t; idx < 16 * 32; idx += 256) {  // s[o][L]
            int o = idx >> 5, L = idx & 31;
            float acc = 0.f;
            for (int i = 0; i < KP; ++i) acc += c[o * KP + i] * P[(o * KP + i) * 33 + L];
            s[idx] = acc;
        }
        __syncthreads();
        if (t < 16) {
            float sq = 0.f;
            for (int L = 0; L < 32; ++L) sq += s[t * 32 + L] * s[t * 32 + L];
            scale[t] = (sq / (1.f + sq)) * (1.0f / sqrtf(sq + 1e-12f));
        }
        __syncthreads();
        for (int idx = t; idx < 16 * 32; idx += 256) v[idx] = s[idx] * scale[idx >> 5];
        __syncthreads();
        if (it < 2) {
            for (int idx = t; idx < 16 * KP; idx += 256) {
                int o = idx / KP, i = idx % KP;
                float acc = 0.f;
                for (int L = 0; L < 32; ++L) acc += P[(o * KP + i) * 33 + L] * v[o * 32 + L];
                logits[idx] += acc;
            }
            __syncthreads();
        }
    }
    for (int idx = t; idx < 16 * 32; idx += 256) v_out[(size_t)b * 512 + idx] = v[idx];
}

// ---------------- capsule-2 priors ----------------
__global__ __launch_bounds__(256) void k_priors2(const float* __restrict__ v1,
                                                 const float* __restrict__ Wc2,
                                                 float* __restrict__ priors2) {
    int b = blockIdx.x;
    __shared__ float ul[16 * 32];
    int t = threadIdx.x;
    for (int idx = t; idx < 512; idx += 256) ul[idx] = v1[(size_t)b * 512 + idx];
    __syncthreads();
    for (int idx = t; idx < NCLS * 16 * 16; idx += 256) {
        int L = idx & 15, i = (idx >> 4) & 15, o = idx >> 8;
        const float* wr = Wc2 + ((size_t)((o * 16 + i) * 16 + L)) * 32;
        const float* ur = &ul[i * 32];
        float acc = 0.f;
        for (int l = 0; l < 32; ++l) acc += wr[l] * ur[l];
        priors2[(size_t)b * (NCLS * 16 * 16) + idx] = acc;
    }
}

// ---------------- capsule-2 routing + final norms ----------------
__global__ __launch_bounds__(256) void k_routing2(const float* __restrict__ priors_g,
                                                  float* __restrict__ out) {
    int b = blockIdx.x;
    __shared__ float P[NCLS * 16 * 17];  // [o][i][L] padded 16->17
    __shared__ float logits[NCLS * 16];
    __shared__ float c[NCLS * 16];
    __shared__ float s[NCLS * 16];
    __shared__ float v[NCLS * 16];
    __shared__ float scale[NCLS];
    int t = threadIdx.x;
    const float* pg = priors_g + (size_t)b * (NCLS * 16 * 16);
    for (int idx = t; idx < NCLS * 16 * 16; idx += 256)
        P[(idx >> 4) * 17 + (idx & 15)] = pg[idx];
    for (int idx = t; idx < NCLS * 16; idx += 256) logits[idx] = 0.f;
    __syncthreads();
    for (int it = 0; it < 3; ++it) {
        if (t < 16) {  // softmax over o for column i=t
            float m = -1e30f;
            for (int o = 0; o < NCLS; ++o) m = fmaxf(m, logits[o * 16 + t]);
            float sum = 0.f;
            for (int o = 0; o < NCLS; ++o) {
                float e = expf(logits[o * 16 + t] - m);
                c[o * 16 + t] = e;
                sum += e;
            }
            for (int o = 0; o < NCLS; ++o) c[o * 16 + t] /= sum;
        }
        __syncthreads();
        if (t < NCLS * 16) {
            int o = t >> 4, L = t & 15;
            float acc = 0.f;
            for (int i = 0; i < 16; ++i) acc += c[o * 16 + i] * P[(o * 16 + i) * 17 + L];
            s[t] = acc;
        }
        __syncthreads();
        if (t < NCLS) {
            float sq = 0.f;
            for (int L = 0; L < 16; ++L) sq += s[t * 16 + L] * s[t * 16 + L];
            scale[t] = (sq / (1.f + sq)) * (1.0f / sqrtf(sq + 1e-12f));
        }
        __syncthreads();
        if (t < NCLS * 16) v[t] = s[t] * scale[t >> 4];
        __syncthreads();
        if (it < 2) {
            if (t < NCLS * 16) {
                int o = t >> 4, i = t & 15;
                float acc = 0.f;
                for (int L = 0; L < 16; ++L) acc += P[(o * 16 + i) * 17 + L] * v[o * 16 + L];
                logits[t] += acc;
            }
            __syncthreads();
        }
    }
    if (t < NCLS) {
        float sq = 0.f;
        for (int L = 0; L < 16; ++L) sq += v[t * 16 + L] * v[t * 16 + L];
        out[(size_t)b * NCLS + t] = sqrtf(sq);
    }
}

extern "C" void kernel_launch(void* const* d_in, const int* in_sizes, int n_in,
                              void* d_out, int out_size, void* d_ws, size_t ws_size,
                              hipStream_t stream) {
    const float* x   = (const float*)d_in[0];
    const int*   ei  = (const int*)d_in[1];   // [2][E], harness converts int64 -> int32
    const float* W1  = (const float*)d_in[3];
    const float* b1  = (const float*)d_in[4];
    const float* W2  = (const float*)d_in[5];
    const float* b2  = (const float*)d_in[6];
    const float* W3  = (const float*)d_in[7];
    const float* b3  = (const float*)d_in[8];
    const float* Wc1 = (const float*)d_in[9];
    const float* Wc2 = (const float*)d_in[10];
    float* out = (float*)d_out;
    float* wsf = (float*)d_ws;

    const int* src = ei;
    const int* dst = ei + NEDGES;

    // workspace layout (float elements)
    int*   deg    = (int*)wsf;                // 100000
    float* dinv   = wsf + 100000;             // 100000
    float* h      = wsf + 200000;             // 3.2M
    float* agg    = wsf + 3400000;            // 3.2M
    float* xc     = wsf + 6600000;            // 9.6M
    float* pooled = wsf + 16200000;           // 2.4M
    float* pr1    = wsf + 18600000;           // 12.8M
    float* v1     = wsf + 31400000;           // 256000
    float* pr2    = wsf + 31656000;           // 1.28M  (end = 32.94M floats ~ 132MB)

    hipMemsetAsync(deg, 0, (size_t)NNODES * sizeof(int), stream);
    k_deg<<<NEDGES / 256, 256, 0, stream>>>(src, dst, deg);
    k_dinv<<<(NNODES + 255) / 256, 256, 0, stream>>>(deg, dinv);

    // ---- layer 1 ----
    k_matmul<<<NNODES / 8, 256, 0, stream>>>(x, FIN, FIN, W1, h);
    hipMemsetAsync(agg, 0, (size_t)NNODES * HID * sizeof(float), stream);
    k_scatter<<<(NEDGES * 8) / 256, 256, 0, stream>>>(src, dst, dinv, h, agg);
    k_finalize<<<NNODES * HID / 256, 256, 0, stream>>>(h, agg, dinv, b1, xc, 0);
    // ---- layer 2 ----
    k_matmul<<<NNODES / 8, 256, 0, stream>>>(xc, 96, HID, W2, h);
    hipMemsetAsync(agg, 0, (size_t)NNODES * HID * sizeof(float), stream);
    k_scatter<<<(NEDGES * 8) / 256, 256, 0, stream>>>(src, dst, dinv, h, agg);
    k_finalize<<<NNODES * HID / 256, 256, 0, stream>>>(h, agg, dinv, b2, xc, 32);
    // ---- layer 3 ----
    k_matmul<<<NNODES / 8, 256, 0, stream>>>(xc + 32, 96, HID, W3, h);
    hipMemsetAsync(agg, 0, (size_t)NNODES * HID * sizeof(float), stream);
    k_scatter<<<(NEDGES * 8) / 256, 256, 0, stream>>>(src, dst, dinv, h, agg);
    k_finalize<<<NNODES * HID / 256, 256, 0, stream>>>(h, agg, dinv, b3, xc, 64);

    // ---- sort-pool + capsules ----
    k_sortpool<<<NGRAPH, 256, 0, stream>>>(xc, pooled);
    k_priors1<<<16 * KP, 256, 0, stream>>>(pooled, Wc1, pr1);
    k_routing1<<<NGRAPH, 256, 0, stream>>>(pr1, v1);
    k_priors2<<<NGRAPH, 256, 0, stream>>>(v1, Wc2, pr2);
    k_routing2<<<NGRAPH, 256, 0, stream>>>(pr2, out);
}

// Round 2
// 1116.639 us; speedup vs baseline: 3.9425x; 3.9425x over previous
//
#include <hip/hip_runtime.h>

#define NNODES 100000
#define NEDGES 3200000
#define NPG 200
#define NGRAPH 500
#define FIN 128
#define HID 32
#define KP 50
#define NCLS 10
#define NB_SCAN 391  // ceil(100000/256)

// ---------------- degree (one int atomic per edge, once) ----------------
__global__ __launch_bounds__(256) void k_deg(const int* __restrict__ src,
                                             const int* __restrict__ dst,
                                             int* __restrict__ deg) {
    int e = blockIdx.x * 256 + threadIdx.x;
    if (e >= NEDGES) return;
    int s = src[e], d = dst[e];
    if (s != d) atomicAdd(&deg[d], 1);
}

__global__ __launch_bounds__(256) void k_dinv(const int* __restrict__ deg,
                                              float* __restrict__ dinv) {
    int n = blockIdx.x * 256 + threadIdx.x;
    if (n >= NNODES) return;
    dinv[n] = 1.0f / sqrtf((float)deg[n] + 1.0f);
}

// ---------------- CSR build: block-level exclusive scan of deg ----------------
__global__ __launch_bounds__(256) void k_blockscan(const int* __restrict__ deg,
                                                   int* __restrict__ offs,
                                                   int* __restrict__ bsum) {
    __shared__ int lds[256];
    int t = threadIdx.x;
    int n = blockIdx.x * 256 + t;
    int v = (n < NNODES) ? deg[n] : 0;
    lds[t] = v;
    __syncthreads();
    for (int ofs = 1; ofs < 256; ofs <<= 1) {
        int add = (t >= ofs) ? lds[t - ofs] : 0;
        __syncthreads();
        lds[t] += add;
        __syncthreads();
    }
    if (n < NNODES) offs[n] = lds[t] - v;  // exclusive within block
    if (t == 255) bsum[blockIdx.x] = lds[255];
}

__global__ __launch_bounds__(512) void k_scanbsum(int* __restrict__ bsum,
                                                  int* __restrict__ offs) {
    __shared__ int lds[512];
    int t = threadIdx.x;
    int v = (t < NB_SCAN) ? bsum[t] : 0;
    lds[t] = v;
    __syncthreads();
    for (int ofs = 1; ofs < 512; ofs <<= 1) {
        int add = (t >= ofs) ? lds[t - ofs] : 0;
        __syncthreads();
        lds[t] += add;
        __syncthreads();
    }
    if (t < NB_SCAN) bsum[t] = lds[t] - v;  // exclusive block bases
    if (t == 511) offs[NNODES] = lds[511];  // total
}

__global__ __launch_bounds__(256) void k_addbase(int* __restrict__ offs,
                                                 const int* __restrict__ bsum) {
    int n = blockIdx.x * 256 + threadIdx.x;
    if (n < NNODES) offs[n] += bsum[blockIdx.x];
}

__global__ __launch_bounds__(256) void k_fill(const int* __restrict__ src,
                                              const int* __restrict__ dst,
                                              const float* __restrict__ dinv,
                                              const int* __restrict__ offs,
                                              int* __restrict__ cursor,
                                              int* __restrict__ csrc,
                                              float* __restrict__ cw) {
    int e = blockIdx.x * 256 + threadIdx.x;
    if (e >= NEDGES) return;
    int s = src[e], d = dst[e];
    if (s == d) return;
    int pos = atomicAdd(&cursor[d], 1);
    int idx = offs[d] + pos;
    csrc[idx] = s;
    cw[idx] = dinv[s] * dinv[d];
}

// ---------------- h = X @ W  (W is K x 32) ----------------
__global__ __launch_bounds__(256) void k_matmul(const float* __restrict__ X, int ldx, int K,
                                                const float* __restrict__ W,
                                                float* __restrict__ h) {
    __shared__ float Wl[FIN * HID];
    int t = threadIdx.x;
    for (int idx = t; idx < K * HID; idx += 256) Wl[idx] = W[idx];
    __syncthreads();
    int n = blockIdx.x * 8 + (t >> 5);
    int j = t & 31;
    const float* xr = X + (size_t)n * ldx;
    float acc = 0.f;
    for (int k = 0; k < K; ++k) acc += xr[k] * Wl[k * HID + j];
    h[n * HID + j] = acc;
}

// ---------------- gather aggregation + finalize (one wave64 per node) ----------------
__global__ __launch_bounds__(256) void k_gather(const int* __restrict__ offs,
                                                const int* __restrict__ csrc,
                                                const float* __restrict__ cw,
                                                const float* __restrict__ h,
                                                const float* __restrict__ dinv,
                                                const float* __restrict__ bias,
                                                float* __restrict__ xc, int coloff) {
    int t = threadIdx.x;
    int n = blockIdx.x * 4 + (t >> 6);
    int lane = t & 63;
    int ch = lane & 31;
    int half = lane >> 5;
    int beg = offs[n], end = offs[n + 1];
    float acc = 0.f;
    for (int e = beg + half; e < end; e += 2) {
        int s = csrc[e];
        float w = cw[e];
        acc += w * h[(size_t)s * HID + ch];
    }
    acc += __shfl_xor(acc, 32, 64);  // combine the two edge-halves (same channel)
    if (half == 0) {
        float di = dinv[n];
        float v = acc + h[(size_t)n * HID + ch] * (di * di) + bias[ch];
        xc[(size_t)n * 96 + coloff + ch] = tanhf(v);
    }
}

// ---------------- stable top-50 sort-pool per graph ----------------
__global__ __launch_bounds__(256) void k_sortpool(const float* __restrict__ xc,
                                                  float* __restrict__ pooled) {
    int g = blockIdx.x;
    __shared__ float vals[NPG];
    __shared__ int ranks[NPG];
    int t = threadIdx.x;
    if (t < NPG) vals[t] = xc[((size_t)g * NPG + t) * 96 + 95];
    __syncthreads();
    if (t < NPG) {
        float v = vals[t];
        int r = 0;
        for (int k = 0; k < NPG; ++k) {
            float vk = vals[k];
            r += (vk > v) || (vk == v && k < t);  // desc value, stable by index
        }
        ranks[t] = r;
    }
    __syncthreads();
    for (int j = 0; j < NPG; ++j) {
        int r = ranks[j];
        if (r < KP && t < 96)
            pooled[((size_t)g * KP + r) * 96 + t] = xc[((size_t)g * NPG + j) * 96 + t];
    }
}

// ---------------- capsule-1 priors: block per (o,i), Wc1 slice in LDS ----------------
__global__ __launch_bounds__(256) void k_priors1(const float* __restrict__ pooled,
                                                 const float* __restrict__ Wc1,
                                                 float* __restrict__ priors) {
    int o = blockIdx.x / KP, i = blockIdx.x % KP;
    __shared__ float Wl[32 * 97];   // padded: bank-conflict-free
    __shared__ float ul[8 * 96];
    int t = threadIdx.x;
    const float* wsrc = Wc1 + ((size_t)(o * KP + i) * 32) * 96;
    for (int idx = t; idx < 32 * 96; idx += 256)
        Wl[(idx / 96) * 97 + (idx % 96)] = wsrc[idx];
    int L = t & 31, bs = t >> 5;
    for (int b0 = 0; b0 < NGRAPH; b0 += 8) {
        __syncthreads();
        for (int idx = t; idx < 8 * 96; idx += 256) {
            int bb = idx / 96, l = idx % 96;
            int b = b0 + bb;
            ul[idx] = (b < NGRAPH) ? pooled[((size_t)b * KP + i) * 96 + l] : 0.f;
        }
        __syncthreads();
        int b = b0 + bs;
        if (b < NGRAPH) {
            const float* wr = &Wl[L * 97];
            const float* ur = &ul[bs * 96];
            float acc = 0.f;
            for (int l = 0; l < 96; ++l) acc += wr[l] * ur[l];
            priors[(((size_t)b * 16 + o) * KP + i) * 32 + L] = acc;
        }
    }
}

// ---------------- capsule-1 routing (per graph, all in LDS) ----------------
__global__ __launch_bounds__(256) void k_routing1(const float* __restrict__ priors_g,
                                                  float* __restrict__ v_out) {
    int b = blockIdx.x;
    __shared__ float P[16 * KP * 33];  // [o][i][L] padded 32->33
    __shared__ float logits[16 * KP];
    __shared__ float c[16 * KP];
    __shared__ float s[16 * 32];
    __shared__ float v[16 * 32];
    __shared__ float scale[16];
    int t = threadIdx.x;
    const float* pg = priors_g + (size_t)b * (16 * KP * 32);
    for (int idx = t; idx < 16 * KP * 32; idx += 256)
        P[(idx >> 5) * 33 + (idx & 31)] = pg[idx];
    for (int idx = t; idx < 16 * KP; idx += 256) logits[idx] = 0.f;
    __syncthreads();
    for (int it = 0; it < 3; ++it) {
        if (t < KP) {  // softmax over o for column i=t
            float m = -1e30f;
            for (int o = 0; o < 16; ++o) m = fmaxf(m, logits[o * KP + t]);
            float sum = 0.f;
            for (int o = 0; o < 16; ++o) {
                float e = expf(logits[o * KP + t] - m);
                c[o * KP + t] = e;
                sum += e;
            }
            for (int o = 0; o < 16; ++o) c[o * KP + t] /= sum;
        }
        __syncthreads();
        for (int idx = t; idx < 16 * 32; idx += 256) {  // s[o][L]
            int o = idx >> 5, L = idx & 31;
            float acc = 0.f;
            for (int i = 0; i < KP; ++i) acc += c[o * KP + i] * P[(o * KP + i) * 33 + L];
            s[idx] = acc;
        }
        __syncthreads();
        if (t < 16) {
            float sq = 0.f;
            for (int L = 0; L < 32; ++L) sq += s[t * 32 + L] * s[t * 32 + L];
            scale[t] = (sq / (1.f + sq)) * (1.0f / sqrtf(sq + 1e-12f));
        }
        __syncthreads();
        for (int idx = t; idx < 16 * 32; idx += 256) v[idx] = s[idx] * scale[idx >> 5];
        __syncthreads();
        if (it < 2) {
            for (int idx = t; idx < 16 * KP; idx += 256) {
                int o = idx / KP, i = idx % KP;
                float acc = 0.f;
                for (int L = 0; L < 32; ++L) acc += P[(o * KP + i) * 33 + L] * v[o * 32 + L];
                logits[idx] += acc;
            }
            __syncthreads();
        }
    }
    for (int idx = t; idx < 16 * 32; idx += 256) v_out[(size_t)b * 512 + idx] = v[idx];
}

// ---------------- capsule-2 priors ----------------
__global__ __launch_bounds__(256) void k_priors2(const float* __restrict__ v1,
                                                 const float* __restrict__ Wc2,
                                                 float* __restrict__ priors2) {
    int b = blockIdx.x;
    __shared__ float ul[16 * 32];
    int t = threadIdx.x;
    for (int idx = t; idx < 512; idx += 256) ul[idx] = v1[(size_t)b * 512 + idx];
    __syncthreads();
    for (int idx = t; idx < NCLS * 16 * 16; idx += 256) {
        int L = idx & 15, i = (idx >> 4) & 15, o = idx >> 8;
        const float* wr = Wc2 + ((size_t)((o * 16 + i) * 16 + L)) * 32;
        const float* ur = &ul[i * 32];
        float acc = 0.f;
        for (int l = 0; l < 32; ++l) acc += wr[l] * ur[l];
        priors2[(size_t)b * (NCLS * 16 * 16) + idx] = acc;
    }
}

// ---------------- capsule-2 routing + final norms ----------------
__global__ __launch_bounds__(256) void k_routing2(const float* __restrict__ priors_g,
                                                  float* __restrict__ out) {
    int b = blockIdx.x;
    __shared__ float P[NCLS * 16 * 17];  // [o][i][L] padded 16->17
    __shared__ float logits[NCLS * 16];
    __shared__ float c[NCLS * 16];
    __shared__ float s[NCLS * 16];
    __shared__ float v[NCLS * 16];
    __shared__ float scale[NCLS];
    int t = threadIdx.x;
    const float* pg = priors_g + (size_t)b * (NCLS * 16 * 16);
    for (int idx = t; idx < NCLS * 16 * 16; idx += 256)
        P[(idx >> 4) * 17 + (idx & 15)] = pg[idx];
    for (int idx = t; idx < NCLS * 16; idx += 256) logits[idx] = 0.f;
    __syncthreads();
    for (int it = 0; it < 3; ++it) {
        if (t < 16) {  // softmax over o for column i=t
            float m = -1e30f;
            for (int o = 0; o < NCLS; ++o) m = fmaxf(m, logits[o * 16 + t]);
            float sum = 0.f;
            for (int o = 0; o < NCLS; ++o) {
                float e = expf(logits[o * 16 + t] - m);
                c[o * 16 + t] = e;
                sum += e;
            }
            for (int o = 0; o < NCLS; ++o) c[o * 16 + t] /= sum;
        }
        __syncthreads();
        if (t < NCLS * 16) {
            int o = t >> 4, L = t & 15;
            float acc = 0.f;
            for (int i = 0; i < 16; ++i) acc += c[o * 16 + i] * P[(o * 16 + i) * 17 + L];
            s[t] = acc;
        }
        __syncthreads();
        if (t < NCLS) {
            float sq = 0.f;
            for (int L = 0; L < 16; ++L) sq += s[t * 16 + L] * s[t * 16 + L];
            scale[t] = (sq / (1.f + sq)) * (1.0f / sqrtf(sq + 1e-12f));
        }
        __syncthreads();
        if (t < NCLS * 16) v[t] = s[t] * scale[t >> 4];
        __syncthreads();
        if (it < 2) {
            if (t < NCLS * 16) {
                int o = t >> 4, i = t & 15;
                float acc = 0.f;
                for (int L = 0; L < 16; ++L) acc += P[(o * 16 + i) * 17 + L] * v[o * 16 + L];
                logits[t] += acc;
            }
            __syncthreads();
        }
    }
    if (t < NCLS) {
        float sq = 0.f;
        for (int L = 0; L < 16; ++L) sq += v[t * 16 + L] * v[t * 16 + L];
        out[(size_t)b * NCLS + t] = sqrtf(sq);
    }
}

extern "C" void kernel_launch(void* const* d_in, const int* in_sizes, int n_in,
                              void* d_out, int out_size, void* d_ws, size_t ws_size,
                              hipStream_t stream) {
    const float* x   = (const float*)d_in[0];
    const int*   ei  = (const int*)d_in[1];
    const float* W1  = (const float*)d_in[3];
    const float* b1  = (const float*)d_in[4];
    const float* W2  = (const float*)d_in[5];
    const float* b2  = (const float*)d_in[6];
    const float* W3  = (const float*)d_in[7];
    const float* b3  = (const float*)d_in[8];
    const float* Wc1 = (const float*)d_in[9];
    const float* Wc2 = (const float*)d_in[10];
    float* out = (float*)d_out;
    float* wsf = (float*)d_ws;

    const int* src = ei;
    const int* dst = ei + NEDGES;

    // ---- workspace layout (float-element offsets) ----
    float* xc = wsf;                    // 9,600,000 floats
    float* R  = wsf + 9600000;          // shared region, phase A vs phase B
    // phase A (GCN):
    int*   deg    = (int*)R;            // 100,000
    float* dinv   = R + 100000;         // 100,000
    int*   offs   = (int*)(R + 200000); // 100,001
    int*   cursor = (int*)(R + 300008); // 100,000
    int*   bsum   = (int*)(R + 400008); // 512
    int*   csrc   = (int*)(R + 400520); // 3,200,000
    float* cw     = R + 3600520;        // 3,200,000
    float* h      = R + 6800520;        // 3,200,000  (16B-aligned: 6800520 % 4 == 0)
    // phase B (capsules) — aliases phase-A region (safe: written after GCN done):
    float* pooled = R;                  // 2,400,000
    float* pr1    = R + 2400000;        // 12,800,000
    float* v1     = R + 15200000;       // 256,000
    float* pr2    = R + 15456000;       // 1,280,000   (total ws use ~105 MB)

    // ---- CSR build (once; shared by all 3 layers) ----
    hipMemsetAsync(deg, 0, (size_t)NNODES * sizeof(int), stream);
    hipMemsetAsync(cursor, 0, (size_t)NNODES * sizeof(int), stream);
    k_deg<<<NEDGES / 256, 256, 0, stream>>>(src, dst, deg);
    k_dinv<<<(NNODES + 255) / 256, 256, 0, stream>>>(deg, dinv);
    k_blockscan<<<NB_SCAN, 256, 0, stream>>>(deg, offs, bsum);
    k_scanbsum<<<1, 512, 0, stream>>>(bsum, offs);
    k_addbase<<<NB_SCAN, 256, 0, stream>>>(offs, bsum);
    k_fill<<<NEDGES / 256, 256, 0, stream>>>(src, dst, dinv, offs, cursor, csrc, cw);

    // ---- layer 1 ----
    k_matmul<<<NNODES / 8, 256, 0, stream>>>(x, FIN, FIN, W1, h);
    k_gather<<<NNODES / 4, 256, 0, stream>>>(offs, csrc, cw, h, dinv, b1, xc, 0);
    // ---- layer 2 ----
    k_matmul<<<NNODES / 8, 256, 0, stream>>>(xc, 96, HID, W2, h);
    k_gather<<<NNODES / 4, 256, 0, stream>>>(offs, csrc, cw, h, dinv, b2, xc, 32);
    // ---- layer 3 ----
    k_matmul<<<NNODES / 8, 256, 0, stream>>>(xc + 32, 96, HID, W3, h);
    k_gather<<<NNODES / 4, 256, 0, stream>>>(offs, csrc, cw, h, dinv, b3, xc, 64);

    // ---- sort-pool + capsules ----
    k_sortpool<<<NGRAPH, 256, 0, stream>>>(xc, pooled);
    k_priors1<<<16 * KP, 256, 0, stream>>>(pooled, Wc1, pr1);
    k_routing1<<<NGRAPH, 256, 0, stream>>>(pr1, v1);
    k_priors2<<<NGRAPH, 256, 0, stream>>>(v1, Wc2, pr2);
    k_routing2<<<NGRAPH, 256, 0, stream>>>(pr2, out);
}

// Round 3
// 855.572 us; speedup vs baseline: 5.1454x; 1.3051x over previous
//
#include <hip/hip_runtime.h>

#define NNODES 100000
#define NEDGES 3200000
#define NPG 200
#define NGRAPH 500
#define FIN 128
#define HID 32
#define KP 50
#define NCLS 10
#define NB_SCAN 391  // ceil(100000/256)

// ---------------- degree (one int atomic per edge, once) ----------------
__global__ __launch_bounds__(256) void k_deg(const int* __restrict__ src,
                                             const int* __restrict__ dst,
                                             int* __restrict__ deg) {
    int e = blockIdx.x * 256 + threadIdx.x;
    if (e >= NEDGES) return;
    int s = src[e], d = dst[e];
    if (s != d) atomicAdd(&deg[d], 1);
}

__global__ __launch_bounds__(256) void k_dinv(const int* __restrict__ deg,
                                              float* __restrict__ dinv) {
    int n = blockIdx.x * 256 + threadIdx.x;
    if (n >= NNODES) return;
    dinv[n] = 1.0f / sqrtf((float)deg[n] + 1.0f);
}

// ---------------- CSR build: block-level exclusive scan of deg ----------------
__global__ __launch_bounds__(256) void k_blockscan(const int* __restrict__ deg,
                                                   int* __restrict__ offs,
                                                   int* __restrict__ bsum) {
    __shared__ int lds[256];
    int t = threadIdx.x;
    int n = blockIdx.x * 256 + t;
    int v = (n < NNODES) ? deg[n] : 0;
    lds[t] = v;
    __syncthreads();
    for (int ofs = 1; ofs < 256; ofs <<= 1) {
        int add = (t >= ofs) ? lds[t - ofs] : 0;
        __syncthreads();
        lds[t] += add;
        __syncthreads();
    }
    if (n < NNODES) offs[n] = lds[t] - v;  // exclusive within block
    if (t == 255) bsum[blockIdx.x] = lds[255];
}

__global__ __launch_bounds__(512) void k_scanbsum(int* __restrict__ bsum,
                                                  int* __restrict__ offs) {
    __shared__ int lds[512];
    int t = threadIdx.x;
    int v = (t < NB_SCAN) ? bsum[t] : 0;
    lds[t] = v;
    __syncthreads();
    for (int ofs = 1; ofs < 512; ofs <<= 1) {
        int add = (t >= ofs) ? lds[t - ofs] : 0;
        __syncthreads();
        lds[t] += add;
        __syncthreads();
    }
    if (t < NB_SCAN) bsum[t] = lds[t] - v;  // exclusive block bases
    if (t == 511) offs[NNODES] = lds[511];  // total
}

__global__ __launch_bounds__(256) void k_addbase(int* __restrict__ offs,
                                                 const int* __restrict__ bsum) {
    int n = blockIdx.x * 256 + threadIdx.x;
    if (n < NNODES) offs[n] += bsum[blockIdx.x];
}

__global__ __launch_bounds__(256) void k_fill(const int* __restrict__ src,
                                              const int* __restrict__ dst,
                                              const int* __restrict__ offs,
                                              int* __restrict__ cursor,
                                              int* __restrict__ csrc) {
    int e = blockIdx.x * 256 + threadIdx.x;
    if (e >= NEDGES) return;
    int s = src[e], d = dst[e];
    if (s == d) return;
    int pos = atomicAdd(&cursor[d], 1);
    csrc[offs[d] + pos] = s;
}

// ---------------- h = X @ W : 64 rows/block, 8 rows/thread ----------------
__global__ __launch_bounds__(256) void k_matmul(const float* __restrict__ X, int ldx, int K,
                                                const float* __restrict__ W,
                                                float* __restrict__ h) {
    __shared__ float Wl[FIN * HID];
    __shared__ float Xl[64 * FIN];
    int t = threadIdx.x;
    for (int idx = t; idx < K * HID; idx += 256) Wl[idx] = W[idx];
    int n0 = blockIdx.x * 64;
    int ng = 64 * K / 4;
    for (int idx = t; idx < ng; idx += 256) {
        int r = (idx * 4) / K, c = (idx * 4) % K;
        float4 v = make_float4(0.f, 0.f, 0.f, 0.f);
        if (n0 + r < NNODES)
            v = *reinterpret_cast<const float4*>(X + (size_t)(n0 + r) * ldx + c);
        *reinterpret_cast<float4*>(&Xl[r * K + c]) = v;
    }
    __syncthreads();
    int j = t & 31, g = t >> 5;  // g in 0..7 -> rows g*8..g*8+7
    const float* xr = &Xl[(g * 8) * K];
    float a0 = 0, a1 = 0, a2 = 0, a3 = 0, a4 = 0, a5 = 0, a6 = 0, a7 = 0;
    for (int k = 0; k < K; ++k) {
        float w = Wl[k * HID + j];
        a0 += w * xr[0 * K + k];
        a1 += w * xr[1 * K + k];
        a2 += w * xr[2 * K + k];
        a3 += w * xr[3 * K + k];
        a4 += w * xr[4 * K + k];
        a5 += w * xr[5 * K + k];
        a6 += w * xr[6 * K + k];
        a7 += w * xr[7 * K + k];
    }
    int r0 = n0 + g * 8;
    float av[8] = {a0, a1, a2, a3, a4, a5, a6, a7};
    for (int q = 0; q < 8; ++q)
        if (r0 + q < NNODES) h[(size_t)(r0 + q) * HID + j] = av[q];
}

// ---------------- gather aggregation + finalize (one wave64 per node) ----------------
__global__ __launch_bounds__(256) void k_gather(const int* __restrict__ offs,
                                                const int* __restrict__ csrc,
                                                const float* __restrict__ dinv,
                                                const float* __restrict__ h,
                                                const float* __restrict__ bias,
                                                float* __restrict__ xc, int coloff) {
    int t = threadIdx.x;
    int n = blockIdx.x * 4 + (t >> 6);
    int lane = t & 63;
    int ch = lane & 31;
    int half = lane >> 5;
    int beg = offs[n], end = offs[n + 1];
    float acc = 0.f;
    int e = beg + half;
    for (; e + 2 < end; e += 4) {  // 2 edges per half per iter
        int s0 = csrc[e], s1 = csrc[e + 2];
        float w0 = dinv[s0], w1 = dinv[s1];
        float h0 = h[(size_t)s0 * HID + ch], h1 = h[(size_t)s1 * HID + ch];
        acc += w0 * h0 + w1 * h1;
    }
    if (e < end) {
        int s = csrc[e];
        acc += dinv[s] * h[(size_t)s * HID + ch];
    }
    acc += __shfl_xor(acc, 32, 64);  // combine edge-halves (same channel)
    if (half == 0) {
        float di = dinv[n];
        float v = di * acc + h[(size_t)n * HID + ch] * (di * di) + bias[ch];
        xc[(size_t)n * 96 + coloff + ch] = tanhf(v);
    }
}

// ---------------- stable top-50 sort-pool per graph ----------------
__global__ __launch_bounds__(256) void k_sortpool(const float* __restrict__ xc,
                                                  float* __restrict__ pooled) {
    int g = blockIdx.x;
    __shared__ float vals[NPG];
    __shared__ int sel[KP];
    int t = threadIdx.x;
    if (t < NPG) vals[t] = xc[((size_t)g * NPG + t) * 96 + 95];
    __syncthreads();
    if (t < NPG) {
        float v = vals[t];
        int r = 0;
        for (int k = 0; k < NPG; ++k) {
            float vk = vals[k];
            r += (vk > v) || (vk == v && k < t);  // desc value, stable by index
        }
        if (r < KP) sel[r] = t;
    }
    __syncthreads();
    for (int idx = t; idx < KP * 96; idx += 256) {
        int r = idx / 96, c = idx % 96;
        pooled[(size_t)g * KP * 96 + idx] = xc[((size_t)g * NPG + sel[r]) * 96 + c];
    }
}

// ---------------- capsule-1 priors as tiled GEMM ----------------
// For fixed i: out[b][c] = sum_l pooled[b,i,l] * Wc1[c>>5, i, c&31, l]
// grid: blockIdx.x = i*64 + bt*8 + ct ; 64x64 tile, 4x4 per thread, K=96
__global__ __launch_bounds__(256) void k_priors1(const float* __restrict__ pooled,
                                                 const float* __restrict__ Wc1,
                                                 float* __restrict__ priors) {
    int bid = blockIdx.x;
    int ct = bid & 7;
    int bt = (bid >> 3) & 7;
    int i = bid >> 6;
    __shared__ float As[96][72];  // k-major, row-dim padded 64->72 (16B-aligned rows)
    __shared__ float Bs[96][72];
    int t = threadIdx.x;
    int rb0 = bt * 64, c0 = ct * 64;
    for (int idx = t; idx < 64 * 24; idx += 256) {
        int r = idx / 24, c4 = (idx % 24) * 4;
        int b = rb0 + r;
        float4 v = make_float4(0.f, 0.f, 0.f, 0.f);
        if (b < NGRAPH)
            v = *reinterpret_cast<const float4*>(pooled + ((size_t)b * KP + i) * 96 + c4);
        As[c4 + 0][r] = v.x;
        As[c4 + 1][r] = v.y;
        As[c4 + 2][r] = v.z;
        As[c4 + 3][r] = v.w;
    }
    for (int idx = t; idx < 64 * 24; idx += 256) {
        int r = idx / 24, c4 = (idx % 24) * 4;
        int c = c0 + r;
        const float* wr = Wc1 + (((size_t)(c >> 5) * KP + i) * 32 + (c & 31)) * 96;
        float4 v = *reinterpret_cast<const float4*>(wr + c4);
        Bs[c4 + 0][r] = v.x;
        Bs[c4 + 1][r] = v.y;
        Bs[c4 + 2][r] = v.z;
        Bs[c4 + 3][r] = v.w;
    }
    __syncthreads();
    int tx = t & 15, ty = t >> 4;
    float4 acc0 = {0, 0, 0, 0}, acc1 = {0, 0, 0, 0}, acc2 = {0, 0, 0, 0}, acc3 = {0, 0, 0, 0};
#pragma unroll 4
    for (int k = 0; k < 96; ++k) {
        float4 ra = *reinterpret_cast<const float4*>(&As[k][ty * 4]);
        float4 rb = *reinterpret_cast<const float4*>(&Bs[k][tx * 4]);
        acc0.x += ra.x * rb.x; acc0.y += ra.x * rb.y; acc0.z += ra.x * rb.z; acc0.w += ra.x * rb.w;
        acc1.x += ra.y * rb.x; acc1.y += ra.y * rb.y; acc1.z += ra.y * rb.z; acc1.w += ra.y * rb.w;
        acc2.x += ra.z * rb.x; acc2.y += ra.z * rb.y; acc2.z += ra.z * rb.z; acc2.w += ra.z * rb.w;
        acc3.x += ra.w * rb.x; acc3.y += ra.w * rb.y; acc3.z += ra.w * rb.z; acc3.w += ra.w * rb.w;
    }
    int c = c0 + tx * 4;
    int o = c >> 5, L = c & 31;  // 4 consecutive L within one o (c%4==0)
    float4 st[4] = {acc0, acc1, acc2, acc3};
    for (int j = 0; j < 4; ++j) {
        int b = rb0 + ty * 4 + j;
        if (b < NGRAPH)
            *reinterpret_cast<float4*>(priors + (((size_t)b * 16 + o) * KP + i) * 32 + L) = st[j];
    }
}

// ---------------- capsule-1 routing (per graph, all in LDS) ----------------
__global__ __launch_bounds__(256) void k_routing1(const float* __restrict__ priors_g,
                                                  float* __restrict__ v_out) {
    int b = blockIdx.x;
    __shared__ float P[16 * KP * 33];  // [o][i][L] padded 32->33
    __shared__ float logits[16 * KP];
    __shared__ float c[16 * KP];
    __shared__ float s[16 * 32];
    __shared__ float v[16 * 32];
    __shared__ float scale[16];
    int t = threadIdx.x;
    const float* pg = priors_g + (size_t)b * (16 * KP * 32);
    for (int idx = t; idx < 16 * KP * 32; idx += 256)
        P[(idx >> 5) * 33 + (idx & 31)] = pg[idx];
    for (int idx = t; idx < 16 * KP; idx += 256) logits[idx] = 0.f;
    __syncthreads();
    for (int it = 0; it < 3; ++it) {
        if (t < KP) {  // softmax over o for column i=t
            float m = -1e30f;
            for (int o = 0; o < 16; ++o) m = fmaxf(m, logits[o * KP + t]);
            float sum = 0.f;
            for (int o = 0; o < 16; ++o) {
                float e = expf(logits[o * KP + t] - m);
                c[o * KP + t] = e;
                sum += e;
            }
            for (int o = 0; o < 16; ++o) c[o * KP + t] /= sum;
        }
        __syncthreads();
        for (int idx = t; idx < 16 * 32; idx += 256) {  // s[o][L]
            int o = idx >> 5, L = idx & 31;
            float acc = 0.f;
            for (int i = 0; i < KP; ++i) acc += c[o * KP + i] * P[(o * KP + i) * 33 + L];
            s[idx] = acc;
        }
        __syncthreads();
        if (t < 16) {
            float sq = 0.f;
            for (int L = 0; L < 32; ++L) sq += s[t * 32 + L] * s[t * 32 + L];
            scale[t] = (sq / (1.f + sq)) * (1.0f / sqrtf(sq + 1e-12f));
        }
        __syncthreads();
        for (int idx = t; idx < 16 * 32; idx += 256) v[idx] = s[idx] * scale[idx >> 5];
        __syncthreads();
        if (it < 2) {
            for (int idx = t; idx < 16 * KP; idx += 256) {
                int o = idx / KP, i = idx % KP;
                float acc = 0.f;
                for (int L = 0; L < 32; ++L) acc += P[(o * KP + i) * 33 + L] * v[o * 32 + L];
                logits[idx] += acc;
            }
            __syncthreads();
        }
    }
    for (int idx = t; idx < 16 * 32; idx += 256) v_out[(size_t)b * 512 + idx] = v[idx];
}

// ---------------- capsule-2 priors ----------------
__global__ __launch_bounds__(256) void k_priors2(const float* __restrict__ v1,
                                                 const float* __restrict__ Wc2,
                                                 float* __restrict__ priors2) {
    int b = blockIdx.x;
    __shared__ float ul[16 * 32];
    int t = threadIdx.x;
    for (int idx = t; idx < 512; idx += 256) ul[idx] = v1[(size_t)b * 512 + idx];
    __syncthreads();
    for (int idx = t; idx < NCLS * 16 * 16; idx += 256) {
        int L = idx & 15, i = (idx >> 4) & 15, o = idx >> 8;
        const float* wr = Wc2 + ((size_t)((o * 16 + i) * 16 + L)) * 32;
        const float* ur = &ul[i * 32];
        float acc = 0.f;
        for (int l = 0; l < 32; ++l) acc += wr[l] * ur[l];
        priors2[(size_t)b * (NCLS * 16 * 16) + idx] = acc;
    }
}

// ---------------- capsule-2 routing + final norms ----------------
__global__ __launch_bounds__(256) void k_routing2(const float* __restrict__ priors_g,
                                                  float* __restrict__ out) {
    int b = blockIdx.x;
    __shared__ float P[NCLS * 16 * 17];  // [o][i][L] padded 16->17
    __shared__ float logits[NCLS * 16];
    __shared__ float c[NCLS * 16];
    __shared__ float s[NCLS * 16];
    __shared__ float v[NCLS * 16];
    __shared__ float scale[NCLS];
    int t = threadIdx.x;
    const float* pg = priors_g + (size_t)b * (NCLS * 16 * 16);
    for (int idx = t; idx < NCLS * 16 * 16; idx += 256)
        P[(idx >> 4) * 17 + (idx & 15)] = pg[idx];
    for (int idx = t; idx < NCLS * 16; idx += 256) logits[idx] = 0.f;
    __syncthreads();
    for (int it = 0; it < 3; ++it) {
        if (t < 16) {
            float m = -1e30f;
            for (int o = 0; o < NCLS; ++o) m = fmaxf(m, logits[o * 16 + t]);
            float sum = 0.f;
            for (int o = 0; o < NCLS; ++o) {
                float e = expf(logits[o * 16 + t] - m);
                c[o * 16 + t] = e;
                sum += e;
            }
            for (int o = 0; o < NCLS; ++o) c[o * 16 + t] /= sum;
        }
        __syncthreads();
        if (t < NCLS * 16) {
            int o = t >> 4, L = t & 15;
            float acc = 0.f;
            for (int i = 0; i < 16; ++i) acc += c[o * 16 + i] * P[(o * 16 + i) * 17 + L];
            s[t] = acc;
        }
        __syncthreads();
        if (t < NCLS) {
            float sq = 0.f;
            for (int L = 0; L < 16; ++L) sq += s[t * 16 + L] * s[t * 16 + L];
            scale[t] = (sq / (1.f + sq)) * (1.0f / sqrtf(sq + 1e-12f));
        }
        __syncthreads();
        if (t < NCLS * 16) v[t] = s[t] * scale[t >> 4];
        __syncthreads();
        if (it < 2) {
            if (t < NCLS * 16) {
                int o = t >> 4, i = t & 15;
                float acc = 0.f;
                for (int L = 0; L < 16; ++L) acc += P[(o * 16 + i) * 17 + L] * v[o * 16 + L];
                logits[t] += acc;
            }
            __syncthreads();
        }
    }
    if (t < NCLS) {
        float sq = 0.f;
        for (int L = 0; L < 16; ++L) sq += v[t * 16 + L] * v[t * 16 + L];
        out[(size_t)b * NCLS + t] = sqrtf(sq);
    }
}

extern "C" void kernel_launch(void* const* d_in, const int* in_sizes, int n_in,
                              void* d_out, int out_size, void* d_ws, size_t ws_size,
                              hipStream_t stream) {
    const float* x   = (const float*)d_in[0];
    const int*   ei  = (const int*)d_in[1];
    const float* W1  = (const float*)d_in[3];
    const float* b1  = (const float*)d_in[4];
    const float* W2  = (const float*)d_in[5];
    const float* b2  = (const float*)d_in[6];
    const float* W3  = (const float*)d_in[7];
    const float* b3  = (const float*)d_in[8];
    const float* Wc1 = (const float*)d_in[9];
    const float* Wc2 = (const float*)d_in[10];
    float* out = (float*)d_out;
    float* wsf = (float*)d_ws;

    const int* src = ei;
    const int* dst = ei + NEDGES;

    // ---- workspace layout (float-element offsets) ----
    float* xc = wsf;                    // 9,600,000
    float* R  = wsf + 9600000;
    // phase A (GCN):
    int*   deg    = (int*)R;            // 100,000
    float* dinv   = R + 100000;         // 100,000
    int*   offs   = (int*)(R + 200000); // 100,001
    int*   cursor = (int*)(R + 300008); // 100,000
    int*   bsum   = (int*)(R + 400008); // 512
    int*   csrc   = (int*)(R + 400520); // 3,200,000
    float* h      = R + 3600520;        // 3,200,000
    // phase B (capsules) — aliases csrc/h region is NOT safe for dinv/offs...
    // pooled starts after h to be safe from nothing: phase B only needs pooled/pr1/v1/pr2.
    float* pooled = R + 6800520;        // 2,400,000
    float* pr1    = R + 9200520;        // 12,800,000
    float* v1     = R + 22000520;       // 256,000
    float* pr2    = R + 22256520;       // 1,280,000  (end ~ 33.1M floats + xc ~ 132 MB)

    // ---- CSR build (once; shared by all 3 layers) ----
    hipMemsetAsync(deg, 0, (size_t)NNODES * sizeof(int), stream);
    hipMemsetAsync(cursor, 0, (size_t)NNODES * sizeof(int), stream);
    k_deg<<<NEDGES / 256, 256, 0, stream>>>(src, dst, deg);
    k_dinv<<<(NNODES + 255) / 256, 256, 0, stream>>>(deg, dinv);
    k_blockscan<<<NB_SCAN, 256, 0, stream>>>(deg, offs, bsum);
    k_scanbsum<<<1, 512, 0, stream>>>(bsum, offs);
    k_addbase<<<NB_SCAN, 256, 0, stream>>>(offs, bsum);
    k_fill<<<NEDGES / 256, 256, 0, stream>>>(src, dst, offs, cursor, csrc);

    // ---- layer 1 ----
    k_matmul<<<(NNODES + 63) / 64, 256, 0, stream>>>(x, FIN, FIN, W1, h);
    k_gather<<<NNODES / 4, 256, 0, stream>>>(offs, csrc, dinv, h, b1, xc, 0);
    // ---- layer 2 ----
    k_matmul<<<(NNODES + 63) / 64, 256, 0, stream>>>(xc, 96, HID, W2, h);
    k_gather<<<NNODES / 4, 256, 0, stream>>>(offs, csrc, dinv, h, b2, xc, 32);
    // ---- layer 3 ----
    k_matmul<<<(NNODES + 63) / 64, 256, 0, stream>>>(xc + 32, 96, HID, W3, h);
    k_gather<<<NNODES / 4, 256, 0, stream>>>(offs, csrc, dinv, h, b3, xc, 64);

    // ---- sort-pool + capsules ----
    k_sortpool<<<NGRAPH, 256, 0, stream>>>(xc, pooled);
    k_priors1<<<50 * 64, 256, 0, stream>>>(pooled, Wc1, pr1);
    k_routing1<<<NGRAPH, 256, 0, stream>>>(pr1, v1);
    k_priors2<<<NGRAPH, 256, 0, stream>>>(v1, Wc2, pr2);
    k_routing2<<<NGRAPH, 256, 0, stream>>>(pr2, out);
}

// Round 4
// 491.062 us; speedup vs baseline: 8.9648x; 1.7423x over previous
//
#include <hip/hip_runtime.h>

#define NNODES 100000
#define NEDGES 3200000
#define NPG 200
#define NGRAPH 500
#define FIN 128
#define HID 32
#define KP 50
#define NCLS 10

#define NB1 196      // ceil(100000/512) dst-buckets
#define BSH 9
#define CHUNK 8192
#define NBLK1 391    // ceil(NEDGES/CHUNK)

// ---------------- level-1: bucket histogram ----------------
__global__ __launch_bounds__(512) void k_hist1(const int* __restrict__ src,
                                               const int* __restrict__ dst,
                                               int* __restrict__ totals) {
    __shared__ int hist[NB1];
    int t = threadIdx.x;
    for (int i = t; i < NB1; i += 512) hist[i] = 0;
    __syncthreads();
    int eb = blockIdx.x * CHUNK;
    for (int i = 0; i < CHUNK / 512; ++i) {
        int e = eb + t + i * 512;
        if (e < NEDGES) {
            int s = src[e], d = dst[e];
            if (s != d) atomicAdd(&hist[d >> BSH], 1);
        }
    }
    __syncthreads();
    for (int i = t; i < NB1; i += 512)
        if (hist[i]) atomicAdd(&totals[i], hist[i]);
}

// ---------------- scan bucket totals -> bstart, init cursor ----------------
__global__ __launch_bounds__(256) void k_scanb(const int* __restrict__ totals,
                                               int* __restrict__ bstart,
                                               int* __restrict__ cursor,
                                               int* __restrict__ offs) {
    __shared__ int lds[256];
    int t = threadIdx.x;
    int v = (t < NB1) ? totals[t] : 0;
    lds[t] = v;
    __syncthreads();
    for (int ofs = 1; ofs < 256; ofs <<= 1) {
        int add = (t >= ofs) ? lds[t - ofs] : 0;
        __syncthreads();
        lds[t] += add;
        __syncthreads();
    }
    if (t <= NB1) {
        int e = (t == 0) ? 0 : lds[t - 1];
        bstart[t] = e;
        if (t < NB1) cursor[t] = e;
    }
    if (t == 0) offs[NNODES] = lds[NB1 - 1];
}

// ---------------- level-1 place: LDS-binned partition, coalesced runs ----------------
__global__ __launch_bounds__(512) void k_place1(const int* __restrict__ src,
                                                const int* __restrict__ dst,
                                                int* __restrict__ cursor,
                                                unsigned* __restrict__ csorted) {
    __shared__ int hist[NB1];
    __shared__ int lstart[NB1];
    __shared__ int base[NB1];
    __shared__ int cnt2[NB1];
    __shared__ int sarr[256];
    __shared__ unsigned buf[CHUNK];
    __shared__ int dbuf[CHUNK];
    int t = threadIdx.x;
    for (int i = t; i < NB1; i += 512) { hist[i] = 0; cnt2[i] = 0; }
    __syncthreads();
    int eb = blockIdx.x * CHUNK;
    for (int i = 0; i < CHUNK / 512; ++i) {
        int e = eb + t + i * 512;
        if (e < NEDGES) {
            int s = src[e], d = dst[e];
            if (s != d) atomicAdd(&hist[d >> BSH], 1);
        }
    }
    __syncthreads();
    if (t < 256) sarr[t] = (t < NB1) ? hist[t] : 0;
    __syncthreads();
    for (int ofs = 1; ofs < 256; ofs <<= 1) {
        int add = (t < 256 && t >= ofs) ? sarr[t - ofs] : 0;
        __syncthreads();
        if (t < 256) sarr[t] += add;
        __syncthreads();
    }
    if (t < NB1) {
        lstart[t] = (t == 0) ? 0 : sarr[t - 1];
        base[t] = hist[t] ? atomicAdd(&cursor[t], hist[t]) : 0;
    }
    __syncthreads();
    for (int i = 0; i < CHUNK / 512; ++i) {
        int e = eb + t + i * 512;
        if (e < NEDGES) {
            int s = src[e], d = dst[e];
            if (s != d) {
                int bk = d >> BSH;
                int pos = atomicAdd(&cnt2[bk], 1);
                int slot = lstart[bk] + pos;
                buf[slot] = ((unsigned)s << BSH) | (unsigned)(d & 511);
                dbuf[slot] = base[bk] + pos;
            }
        }
    }
    __syncthreads();
    int nval = sarr[NB1 - 1];
    for (int j = t; j < nval; j += 512) csorted[dbuf[j]] = buf[j];
}

// ---------------- level-2: per-bucket CSR finalize (+offs, +dinv) ----------------
__global__ __launch_bounds__(512) void k_fill2(const int* __restrict__ bstart,
                                               const unsigned* __restrict__ csorted,
                                               int* __restrict__ csrc,
                                               int* __restrict__ offs,
                                               float* __restrict__ dinv) {
    __shared__ int cnt[512];
    __shared__ int loffs[512];
    __shared__ int cnt2[512];
    __shared__ int sarr[512];
    int b = blockIdx.x, t = threadIdx.x;
    cnt[t] = 0; cnt2[t] = 0;
    __syncthreads();
    int s0 = bstart[b], s1 = bstart[b + 1];
    for (int j = s0 + t; j < s1; j += 512) atomicAdd(&cnt[csorted[j] & 511], 1);
    __syncthreads();
    sarr[t] = cnt[t];
    __syncthreads();
    for (int ofs = 1; ofs < 512; ofs <<= 1) {
        int add = (t >= ofs) ? sarr[t - ofs] : 0;
        __syncthreads();
        sarr[t] += add;
        __syncthreads();
    }
    loffs[t] = sarr[t] - cnt[t];  // exclusive
    __syncthreads();
    int n = b * 512 + t;
    if (n < NNODES) {
        offs[n] = s0 + loffs[t];
        dinv[n] = rsqrtf((float)cnt[t] + 1.0f);
    }
    for (int j = s0 + t; j < s1; j += 512) {
        unsigned p = csorted[j];
        int d = p & 511;
        int pos = atomicAdd(&cnt2[d], 1);
        csrc[s0 + loffs[d] + pos] = (int)(p >> BSH);
    }
}

// ---------------- h = X @ W : 64 rows/block, 8 rows/thread ----------------
__global__ __launch_bounds__(256) void k_matmul(const float* __restrict__ X, int ldx, int K,
                                                const float* __restrict__ W,
                                                float* __restrict__ h) {
    __shared__ float Wl[FIN * HID];
    __shared__ float Xl[64 * FIN];
    int t = threadIdx.x;
    for (int idx = t; idx < K * HID; idx += 256) Wl[idx] = W[idx];
    int n0 = blockIdx.x * 64;
    int ng = 64 * K / 4;
    for (int idx = t; idx < ng; idx += 256) {
        int r = (idx * 4) / K, c = (idx * 4) % K;
        float4 v = make_float4(0.f, 0.f, 0.f, 0.f);
        if (n0 + r < NNODES)
            v = *reinterpret_cast<const float4*>(X + (size_t)(n0 + r) * ldx + c);
        *reinterpret_cast<float4*>(&Xl[r * K + c]) = v;
    }
    __syncthreads();
    int j = t & 31, g = t >> 5;
    const float* xr = &Xl[(g * 8) * K];
    float a0 = 0, a1 = 0, a2 = 0, a3 = 0, a4 = 0, a5 = 0, a6 = 0, a7 = 0;
    for (int k = 0; k < K; ++k) {
        float w = Wl[k * HID + j];
        a0 += w * xr[0 * K + k];
        a1 += w * xr[1 * K + k];
        a2 += w * xr[2 * K + k];
        a3 += w * xr[3 * K + k];
        a4 += w * xr[4 * K + k];
        a5 += w * xr[5 * K + k];
        a6 += w * xr[6 * K + k];
        a7 += w * xr[7 * K + k];
    }
    int r0 = n0 + g * 8;
    float av[8] = {a0, a1, a2, a3, a4, a5, a6, a7};
    for (int q = 0; q < 8; ++q)
        if (r0 + q < NNODES) h[(size_t)(r0 + q) * HID + j] = av[q];
}

// ---------------- gather: 8 edges/wave-instr, float4 channels ----------------
__global__ __launch_bounds__(256) void k_gather(const int* __restrict__ offs,
                                                const int* __restrict__ csrc,
                                                const float* __restrict__ dinv,
                                                const float* __restrict__ h,
                                                const float* __restrict__ bias,
                                                float* __restrict__ xc, int coloff) {
    int t = threadIdx.x;
    int n = blockIdx.x * 4 + (t >> 6);
    int lane = t & 63;
    int g = lane >> 3;   // edge slot 0..7
    int q = lane & 7;    // channel quad 0..7
    int beg = offs[n], end = offs[n + 1];
    float4 acc = make_float4(0.f, 0.f, 0.f, 0.f);
    for (int e = beg + g; e < end; e += 8) {
        int s = csrc[e];
        float w = dinv[s];
        float4 hv = *reinterpret_cast<const float4*>(h + (size_t)s * HID + q * 4);
        acc.x += w * hv.x; acc.y += w * hv.y; acc.z += w * hv.z; acc.w += w * hv.w;
    }
    for (int m = 8; m <= 32; m <<= 1) {
        acc.x += __shfl_xor(acc.x, m, 64);
        acc.y += __shfl_xor(acc.y, m, 64);
        acc.z += __shfl_xor(acc.z, m, 64);
        acc.w += __shfl_xor(acc.w, m, 64);
    }
    if (g == 0) {
        float di = dinv[n];
        float dd = di * di;
        float4 hv = *reinterpret_cast<const float4*>(h + (size_t)n * HID + q * 4);
        float4 bv = *reinterpret_cast<const float4*>(bias + q * 4);
        float4 v;
        v.x = tanhf(di * acc.x + hv.x * dd + bv.x);
        v.y = tanhf(di * acc.y + hv.y * dd + bv.y);
        v.z = tanhf(di * acc.z + hv.z * dd + bv.z);
        v.w = tanhf(di * acc.w + hv.w * dd + bv.w);
        *reinterpret_cast<float4*>(xc + (size_t)n * 96 + coloff + q * 4) = v;
    }
}

// ---------------- stable top-50 sort-pool per graph ----------------
__global__ __launch_bounds__(256) void k_sortpool(const float* __restrict__ xc,
                                                  float* __restrict__ pooled) {
    int g = blockIdx.x;
    __shared__ float vals[NPG];
    __shared__ int sel[KP];
    int t = threadIdx.x;
    if (t < NPG) vals[t] = xc[((size_t)g * NPG + t) * 96 + 95];
    __syncthreads();
    if (t < NPG) {
        float v = vals[t];
        int r = 0;
        for (int k = 0; k < NPG; ++k) {
            float vk = vals[k];
            r += (vk > v) || (vk == v && k < t);
        }
        if (r < KP) sel[r] = t;
    }
    __syncthreads();
    for (int idx = t; idx < KP * 24; idx += 256) {
        int r = idx / 24, c4 = (idx % 24) * 4;
        *reinterpret_cast<float4*>(pooled + (size_t)g * KP * 96 + r * 96 + c4) =
            *reinterpret_cast<const float4*>(xc + ((size_t)g * NPG + sel[r]) * 96 + c4);
    }
}

// ---------------- capsule-1 priors as tiled GEMM ----------------
__global__ __launch_bounds__(256) void k_priors1(const float* __restrict__ pooled,
                                                 const float* __restrict__ Wc1,
                                                 float* __restrict__ priors) {
    int bid = blockIdx.x;
    int ct = bid & 7;
    int bt = (bid >> 3) & 7;
    int i = bid >> 6;
    __shared__ float As[96][72];
    __shared__ float Bs[96][72];
    int t = threadIdx.x;
    int rb0 = bt * 64, c0 = ct * 64;
    for (int idx = t; idx < 64 * 24; idx += 256) {
        int r = idx / 24, c4 = (idx % 24) * 4;
        int b = rb0 + r;
        float4 v = make_float4(0.f, 0.f, 0.f, 0.f);
        if (b < NGRAPH)
            v = *reinterpret_cast<const float4*>(pooled + ((size_t)b * KP + i) * 96 + c4);
        As[c4 + 0][r] = v.x;
        As[c4 + 1][r] = v.y;
        As[c4 + 2][r] = v.z;
        As[c4 + 3][r] = v.w;
    }
    for (int idx = t; idx < 64 * 24; idx += 256) {
        int r = idx / 24, c4 = (idx % 24) * 4;
        int c = c0 + r;
        const float* wr = Wc1 + (((size_t)(c >> 5) * KP + i) * 32 + (c & 31)) * 96;
        float4 v = *reinterpret_cast<const float4*>(wr + c4);
        Bs[c4 + 0][r] = v.x;
        Bs[c4 + 1][r] = v.y;
        Bs[c4 + 2][r] = v.z;
        Bs[c4 + 3][r] = v.w;
    }
    __syncthreads();
    int tx = t & 15, ty = t >> 4;
    float4 acc0 = {0, 0, 0, 0}, acc1 = {0, 0, 0, 0}, acc2 = {0, 0, 0, 0}, acc3 = {0, 0, 0, 0};
#pragma unroll 4
    for (int k = 0; k < 96; ++k) {
        float4 ra = *reinterpret_cast<const float4*>(&As[k][ty * 4]);
        float4 rb = *reinterpret_cast<const float4*>(&Bs[k][tx * 4]);
        acc0.x += ra.x * rb.x; acc0.y += ra.x * rb.y; acc0.z += ra.x * rb.z; acc0.w += ra.x * rb.w;
        acc1.x += ra.y * rb.x; acc1.y += ra.y * rb.y; acc1.z += ra.y * rb.z; acc1.w += ra.y * rb.w;
        acc2.x += ra.z * rb.x; acc2.y += ra.z * rb.y; acc2.z += ra.z * rb.z; acc2.w += ra.z * rb.w;
        acc3.x += ra.w * rb.x; acc3.y += ra.w * rb.y; acc3.z += ra.w * rb.z; acc3.w += ra.w * rb.w;
    }
    int c = c0 + tx * 4;
    int o = c >> 5, L = c & 31;
    float4 st[4] = {acc0, acc1, acc2, acc3};
    for (int j = 0; j < 4; ++j) {
        int b = rb0 + ty * 4 + j;
        if (b < NGRAPH)
            *reinterpret_cast<float4*>(priors + (((size_t)b * 16 + o) * KP + i) * 32 + L) = st[j];
    }
}

// ---------------- capsule-1 routing (per graph, all in LDS) ----------------
__global__ __launch_bounds__(256) void k_routing1(const float* __restrict__ priors_g,
                                                  float* __restrict__ v_out) {
    int b = blockIdx.x;
    __shared__ float P[16 * KP * 33];
    __shared__ float logits[16 * KP];
    __shared__ float c[16 * KP];
    __shared__ float s[16 * 32];
    __shared__ float v[16 * 32];
    __shared__ float scale[16];
    int t = threadIdx.x;
    const float* pg = priors_g + (size_t)b * (16 * KP * 32);
    for (int idx = t; idx < 16 * KP * 32; idx += 256)
        P[(idx >> 5) * 33 + (idx & 31)] = pg[idx];
    for (int idx = t; idx < 16 * KP; idx += 256) logits[idx] = 0.f;
    __syncthreads();
    for (int it = 0; it < 3; ++it) {
        if (t < KP) {
            float m = -1e30f;
            for (int o = 0; o < 16; ++o) m = fmaxf(m, logits[o * KP + t]);
            float sum = 0.f;
            for (int o = 0; o < 16; ++o) {
                float e = expf(logits[o * KP + t] - m);
                c[o * KP + t] = e;
                sum += e;
            }
            for (int o = 0; o < 16; ++o) c[o * KP + t] /= sum;
        }
        __syncthreads();
        for (int idx = t; idx < 16 * 32; idx += 256) {
            int o = idx >> 5, L = idx & 31;
            float acc = 0.f;
            for (int i = 0; i < KP; ++i) acc += c[o * KP + i] * P[(o * KP + i) * 33 + L];
            s[idx] = acc;
        }
        __syncthreads();
        if (t < 16) {
            float sq = 0.f;
            for (int L = 0; L < 32; ++L) sq += s[t * 32 + L] * s[t * 32 + L];
            scale[t] = (sq / (1.f + sq)) * (1.0f / sqrtf(sq + 1e-12f));
        }
        __syncthreads();
        for (int idx = t; idx < 16 * 32; idx += 256) v[idx] = s[idx] * scale[idx >> 5];
        __syncthreads();
        if (it < 2) {
            for (int idx = t; idx < 16 * KP; idx += 256) {
                int o = idx / KP, i = idx % KP;
                float acc = 0.f;
                for (int L = 0; L < 32; ++L) acc += P[(o * KP + i) * 33 + L] * v[o * 32 + L];
                logits[idx] += acc;
            }
            __syncthreads();
        }
    }
    for (int idx = t; idx < 16 * 32; idx += 256) v_out[(size_t)b * 512 + idx] = v[idx];
}

// ---------------- capsule-2 priors ----------------
__global__ __launch_bounds__(256) void k_priors2(const float* __restrict__ v1,
                                                 const float* __restrict__ Wc2,
                                                 float* __restrict__ priors2) {
    int b = blockIdx.x;
    __shared__ float ul[16 * 32];
    int t = threadIdx.x;
    for (int idx = t; idx < 512; idx += 256) ul[idx] = v1[(size_t)b * 512 + idx];
    __syncthreads();
    for (int idx = t; idx < NCLS * 16 * 16; idx += 256) {
        int L = idx & 15, i = (idx >> 4) & 15, o = idx >> 8;
        const float* wr = Wc2 + ((size_t)((o * 16 + i) * 16 + L)) * 32;
        const float* ur = &ul[i * 32];
        float acc = 0.f;
        for (int l = 0; l < 32; ++l) acc += wr[l] * ur[l];
        priors2[(size_t)b * (NCLS * 16 * 16) + idx] = acc;
    }
}

// ---------------- capsule-2 routing + final norms ----------------
__global__ __launch_bounds__(256) void k_routing2(const float* __restrict__ priors_g,
                                                  float* __restrict__ out) {
    int b = blockIdx.x;
    __shared__ float P[NCLS * 16 * 17];
    __shared__ float logits[NCLS * 16];
    __shared__ float c[NCLS * 16];
    __shared__ float s[NCLS * 16];
    __shared__ float v[NCLS * 16];
    __shared__ float scale[NCLS];
    int t = threadIdx.x;
    const float* pg = priors_g + (size_t)b * (NCLS * 16 * 16);
    for (int idx = t; idx < NCLS * 16 * 16; idx += 256)
        P[(idx >> 4) * 17 + (idx & 15)] = pg[idx];
    for (int idx = t; idx < NCLS * 16; idx += 256) logits[idx] = 0.f;
    __syncthreads();
    for (int it = 0; it < 3; ++it) {
        if (t < 16) {
            float m = -1e30f;
            for (int o = 0; o < NCLS; ++o) m = fmaxf(m, logits[o * 16 + t]);
            float sum = 0.f;
            for (int o = 0; o < NCLS; ++o) {
                float e = expf(logits[o * 16 + t] - m);
                c[o * 16 + t] = e;
                sum += e;
            }
            for (int o = 0; o < NCLS; ++o) c[o * 16 + t] /= sum;
        }
        __syncthreads();
        if (t < NCLS * 16) {
            int o = t >> 4, L = t & 15;
            float acc = 0.f;
            for (int i = 0; i < 16; ++i) acc += c[o * 16 + i] * P[(o * 16 + i) * 17 + L];
            s[t] = acc;
        }
        __syncthreads();
        if (t < NCLS) {
            float sq = 0.f;
            for (int L = 0; L < 16; ++L) sq += s[t * 16 + L] * s[t * 16 + L];
            scale[t] = (sq / (1.f + sq)) * (1.0f / sqrtf(sq + 1e-12f));
        }
        __syncthreads();
        if (t < NCLS * 16) v[t] = s[t] * scale[t >> 4];
        __syncthreads();
        if (it < 2) {
            if (t < NCLS * 16) {
                int o = t >> 4, i = t & 15;
                float acc = 0.f;
                for (int L = 0; L < 16; ++L) acc += P[(o * 16 + i) * 17 + L] * v[o * 16 + L];
                logits[t] += acc;
            }
            __syncthreads();
        }
    }
    if (t < NCLS) {
        float sq = 0.f;
        for (int L = 0; L < 16; ++L) sq += v[t * 16 + L] * v[t * 16 + L];
        out[(size_t)b * NCLS + t] = sqrtf(sq);
    }
}

extern "C" void kernel_launch(void* const* d_in, const int* in_sizes, int n_in,
                              void* d_out, int out_size, void* d_ws, size_t ws_size,
                              hipStream_t stream) {
    const float* x   = (const float*)d_in[0];
    const int*   ei  = (const int*)d_in[1];
    const float* W1  = (const float*)d_in[3];
    const float* b1  = (const float*)d_in[4];
    const float* W2  = (const float*)d_in[5];
    const float* b2  = (const float*)d_in[6];
    const float* W3  = (const float*)d_in[7];
    const float* b3  = (const float*)d_in[8];
    const float* Wc1 = (const float*)d_in[9];
    const float* Wc2 = (const float*)d_in[10];
    float* out = (float*)d_out;
    float* wsf = (float*)d_ws;

    const int* src = ei;
    const int* dst = ei + NEDGES;

    // ---- workspace layout (float-element offsets) ----
    float*    xc      = wsf;                        // 9,600,000
    float*    R       = wsf + 9600000;
    int*      totals  = (int*)R;                    // 196
    int*      bstart  = (int*)(R + 200);            // 197
    int*      cursor  = (int*)(R + 400);            // 196
    float*    dinv    = R + 600;                    // 100,000
    int*      offs    = (int*)(R + 100600);         // 100,001
    unsigned* csorted = (unsigned*)(R + 200608);    // 3,200,000 (dead after k_fill2)
    int*      csrc    = (int*)(R + 3400608);        // 3,200,000
    float*    h       = R + 6600608;                // 3,200,000
    // phase B: pooled aliases the dead csorted region
    float*    pooled  = R + 200608;                 // 2,400,000
    float*    pr1     = R + 9800608;                // 12,800,000
    float*    v1      = R + 22600608;               // 256,000
    float*    pr2     = R + 22856608;               // 1,280,000  (end ~135 MB total)

    // ---- CSR build: bucketed two-level (coalesced writes) ----
    hipMemsetAsync(totals, 0, NB1 * sizeof(int), stream);
    k_hist1<<<NBLK1, 512, 0, stream>>>(src, dst, totals);
    k_scanb<<<1, 256, 0, stream>>>(totals, bstart, cursor, offs);
    k_place1<<<NBLK1, 512, 0, stream>>>(src, dst, cursor, csorted);
    k_fill2<<<NB1, 512, 0, stream>>>(bstart, csorted, csrc, offs, dinv);

    // ---- layer 1 ----
    k_matmul<<<(NNODES + 63) / 64, 256, 0, stream>>>(x, FIN, FIN, W1, h);
    k_gather<<<NNODES / 4, 256, 0, stream>>>(offs, csrc, dinv, h, b1, xc, 0);
    // ---- layer 2 ----
    k_matmul<<<(NNODES + 63) / 64, 256, 0, stream>>>(xc, 96, HID, W2, h);
    k_gather<<<NNODES / 4, 256, 0, stream>>>(offs, csrc, dinv, h, b2, xc, 32);
    // ---- layer 3 ----
    k_matmul<<<(NNODES + 63) / 64, 256, 0, stream>>>(xc + 32, 96, HID, W3, h);
    k_gather<<<NNODES / 4, 256, 0, stream>>>(offs, csrc, dinv, h, b3, xc, 64);

    // ---- sort-pool + capsules ----
    k_sortpool<<<NGRAPH, 256, 0, stream>>>(xc, pooled);
    k_priors1<<<50 * 64, 256, 0, stream>>>(pooled, Wc1, pr1);
    k_routing1<<<NGRAPH, 256, 0, stream>>>(pr1, v1);
    k_priors2<<<NGRAPH, 256, 0, stream>>>(v1, Wc2, pr2);
    k_routing2<<<NGRAPH, 256, 0, stream>>>(pr2, out);
}

// Round 5
// 469.045 us; speedup vs baseline: 9.3857x; 1.0469x over previous
//
#include <hip/hip_runtime.h>

#define NNODES 100000
#define NEDGES 3200000
#define NPG 200
#define NGRAPH 500
#define FIN 128
#define HID 32
#define KP 50
#define NCLS 10

#define NB1 196      // ceil(100000/512) dst-buckets
#define BSH 9
#define CHUNK 8192
#define NBLK1 391    // ceil(NEDGES/CHUNK)

// ---------------- level-1: bucket histogram ----------------
__global__ __launch_bounds__(512) void k_hist1(const int* __restrict__ src,
                                               const int* __restrict__ dst,
                                               int* __restrict__ totals) {
    __shared__ int hist[NB1];
    int t = threadIdx.x;
    for (int i = t; i < NB1; i += 512) hist[i] = 0;
    __syncthreads();
    int eb = blockIdx.x * CHUNK;
    for (int i = 0; i < CHUNK / 512; ++i) {
        int e = eb + t + i * 512;
        if (e < NEDGES) {
            int s = src[e], d = dst[e];
            if (s != d) atomicAdd(&hist[d >> BSH], 1);
        }
    }
    __syncthreads();
    for (int i = t; i < NB1; i += 512)
        if (hist[i]) atomicAdd(&totals[i], hist[i]);
}

// ---------------- scan bucket totals -> bstart, init cursor ----------------
__global__ __launch_bounds__(256) void k_scanb(const int* __restrict__ totals,
                                               int* __restrict__ bstart,
                                               int* __restrict__ cursor,
                                               int* __restrict__ offs) {
    __shared__ int lds[256];
    int t = threadIdx.x;
    int v = (t < NB1) ? totals[t] : 0;
    lds[t] = v;
    __syncthreads();
    for (int ofs = 1; ofs < 256; ofs <<= 1) {
        int add = (t >= ofs) ? lds[t - ofs] : 0;
        __syncthreads();
        lds[t] += add;
        __syncthreads();
    }
    if (t <= NB1) {
        int e = (t == 0) ? 0 : lds[t - 1];
        bstart[t] = e;
        if (t < NB1) cursor[t] = e;
    }
    if (t == 0) offs[NNODES] = lds[NB1 - 1];
}

// ---------------- level-1 place: LDS-binned partition, coalesced runs ----------------
__global__ __launch_bounds__(512) void k_place1(const int* __restrict__ src,
                                                const int* __restrict__ dst,
                                                int* __restrict__ cursor,
                                                unsigned* __restrict__ csorted) {
    __shared__ int hist[NB1];
    __shared__ int lstart[NB1];
    __shared__ int base[NB1];
    __shared__ int cnt2[NB1];
    __shared__ int sarr[256];
    __shared__ unsigned buf[CHUNK];
    __shared__ int dbuf[CHUNK];
    int t = threadIdx.x;
    for (int i = t; i < NB1; i += 512) { hist[i] = 0; cnt2[i] = 0; }
    __syncthreads();
    int eb = blockIdx.x * CHUNK;
    for (int i = 0; i < CHUNK / 512; ++i) {
        int e = eb + t + i * 512;
        if (e < NEDGES) {
            int s = src[e], d = dst[e];
            if (s != d) atomicAdd(&hist[d >> BSH], 1);
        }
    }
    __syncthreads();
    if (t < 256) sarr[t] = (t < NB1) ? hist[t] : 0;
    __syncthreads();
    for (int ofs = 1; ofs < 256; ofs <<= 1) {
        int add = (t < 256 && t >= ofs) ? sarr[t - ofs] : 0;
        __syncthreads();
        if (t < 256) sarr[t] += add;
        __syncthreads();
    }
    if (t < NB1) {
        lstart[t] = (t == 0) ? 0 : sarr[t - 1];
        base[t] = hist[t] ? atomicAdd(&cursor[t], hist[t]) : 0;
    }
    __syncthreads();
    for (int i = 0; i < CHUNK / 512; ++i) {
        int e = eb + t + i * 512;
        if (e < NEDGES) {
            int s = src[e], d = dst[e];
            if (s != d) {
                int bk = d >> BSH;
                int pos = atomicAdd(&cnt2[bk], 1);
                int slot = lstart[bk] + pos;
                buf[slot] = ((unsigned)s << BSH) | (unsigned)(d & 511);
                dbuf[slot] = base[bk] + pos;
            }
        }
    }
    __syncthreads();
    int nval = sarr[NB1 - 1];
    for (int j = t; j < nval; j += 512) csorted[dbuf[j]] = buf[j];
}

// ---------------- level-2: per-bucket CSR finalize (+offs, +dinv) ----------------
__global__ __launch_bounds__(512) void k_fill2(const int* __restrict__ bstart,
                                               const unsigned* __restrict__ csorted,
                                               int* __restrict__ csrc,
                                               int* __restrict__ offs,
                                               float* __restrict__ dinv) {
    __shared__ int cnt[512];
    __shared__ int loffs[512];
    __shared__ int cnt2[512];
    __shared__ int sarr[512];
    int b = blockIdx.x, t = threadIdx.x;
    cnt[t] = 0; cnt2[t] = 0;
    __syncthreads();
    int s0 = bstart[b], s1 = bstart[b + 1];
    for (int j = s0 + t; j < s1; j += 512) atomicAdd(&cnt[csorted[j] & 511], 1);
    __syncthreads();
    sarr[t] = cnt[t];
    __syncthreads();
    for (int ofs = 1; ofs < 512; ofs <<= 1) {
        int add = (t >= ofs) ? sarr[t - ofs] : 0;
        __syncthreads();
        sarr[t] += add;
        __syncthreads();
    }
    loffs[t] = sarr[t] - cnt[t];  // exclusive
    __syncthreads();
    int n = b * 512 + t;
    if (n < NNODES) {
        offs[n] = s0 + loffs[t];
        dinv[n] = rsqrtf((float)cnt[t] + 1.0f);
    }
    for (int j = s0 + t; j < s1; j += 512) {
        unsigned p = csorted[j];
        int d = p & 511;
        int pos = atomicAdd(&cnt2[d], 1);
        csrc[s0 + loffs[d] + pos] = (int)(p >> BSH);
    }
}

// ---------------- hw = (X @ W) * dinv : 64 rows/block, 8 rows/thread ----------------
__global__ __launch_bounds__(256) void k_matmul(const float* __restrict__ X, int ldx, int K,
                                                const float* __restrict__ W,
                                                const float* __restrict__ dinv,
                                                float* __restrict__ h) {
    __shared__ float Wl[FIN * HID];
    __shared__ float Xl[64 * FIN];
    int t = threadIdx.x;
    for (int idx = t; idx < K * HID; idx += 256) Wl[idx] = W[idx];
    int n0 = blockIdx.x * 64;
    int ng = 64 * K / 4;
    for (int idx = t; idx < ng; idx += 256) {
        int r = (idx * 4) / K, c = (idx * 4) % K;
        float4 v = make_float4(0.f, 0.f, 0.f, 0.f);
        if (n0 + r < NNODES)
            v = *reinterpret_cast<const float4*>(X + (size_t)(n0 + r) * ldx + c);
        *reinterpret_cast<float4*>(&Xl[r * K + c]) = v;
    }
    __syncthreads();
    int j = t & 31, g = t >> 5;
    const float* xr = &Xl[(g * 8) * K];
    float a0 = 0, a1 = 0, a2 = 0, a3 = 0, a4 = 0, a5 = 0, a6 = 0, a7 = 0;
    for (int k = 0; k < K; ++k) {
        float w = Wl[k * HID + j];
        a0 += w * xr[0 * K + k];
        a1 += w * xr[1 * K + k];
        a2 += w * xr[2 * K + k];
        a3 += w * xr[3 * K + k];
        a4 += w * xr[4 * K + k];
        a5 += w * xr[5 * K + k];
        a6 += w * xr[6 * K + k];
        a7 += w * xr[7 * K + k];
    }
    int r0 = n0 + g * 8;
    float av[8] = {a0, a1, a2, a3, a4, a5, a6, a7};
    for (int q = 0; q < 8; ++q)
        if (r0 + q < NNODES) h[(size_t)(r0 + q) * HID + j] = av[q] * dinv[r0 + q];
}

// ---------------- gather: hw pre-scaled by dinv[src]; 8 edges/wave-iter ----------------
__global__ __launch_bounds__(256) void k_gather(const int* __restrict__ offs,
                                                const int* __restrict__ csrc,
                                                const float* __restrict__ dinv,
                                                const float* __restrict__ hw,
                                                const float* __restrict__ bias,
                                                float* __restrict__ xc, int coloff) {
    int t = threadIdx.x;
    int n = blockIdx.x * 4 + (t >> 6);
    int lane = t & 63;
    int g = lane >> 3;   // edge slot 0..7
    int q = lane & 7;    // channel quad 0..7
    int beg = offs[n], end = offs[n + 1];
    float4 acc = make_float4(0.f, 0.f, 0.f, 0.f);
    for (int e = beg + g; e < end; e += 8) {
        int s = csrc[e];
        float4 hv = *reinterpret_cast<const float4*>(hw + (size_t)s * HID + q * 4);
        acc.x += hv.x; acc.y += hv.y; acc.z += hv.z; acc.w += hv.w;
    }
    for (int m = 8; m <= 32; m <<= 1) {
        acc.x += __shfl_xor(acc.x, m, 64);
        acc.y += __shfl_xor(acc.y, m, 64);
        acc.z += __shfl_xor(acc.z, m, 64);
        acc.w += __shfl_xor(acc.w, m, 64);
    }
    if (g == 0) {
        float di = dinv[n];
        float4 hv = *reinterpret_cast<const float4*>(hw + (size_t)n * HID + q * 4);
        float4 bv = *reinterpret_cast<const float4*>(bias + q * 4);
        float4 v;
        v.x = tanhf(di * (acc.x + hv.x) + bv.x);
        v.y = tanhf(di * (acc.y + hv.y) + bv.y);
        v.z = tanhf(di * (acc.z + hv.z) + bv.z);
        v.w = tanhf(di * (acc.w + hv.w) + bv.w);
        *reinterpret_cast<float4*>(xc + (size_t)n * 96 + coloff + q * 4) = v;
    }
}

// ---------------- stable top-50 sort-pool per graph ----------------
__global__ __launch_bounds__(256) void k_sortpool(const float* __restrict__ xc,
                                                  float* __restrict__ pooled) {
    int g = blockIdx.x;
    __shared__ float vals[NPG];
    __shared__ int sel[KP];
    int t = threadIdx.x;
    if (t < NPG) vals[t] = xc[((size_t)g * NPG + t) * 96 + 95];
    __syncthreads();
    if (t < NPG) {
        float v = vals[t];
        int r = 0;
        for (int k = 0; k < NPG; ++k) {
            float vk = vals[k];
            r += (vk > v) || (vk == v && k < t);
        }
        if (r < KP) sel[r] = t;
    }
    __syncthreads();
    for (int idx = t; idx < KP * 24; idx += 256) {
        int r = idx / 24, c4 = (idx % 24) * 4;
        *reinterpret_cast<float4*>(pooled + (size_t)g * KP * 96 + r * 96 + c4) =
            *reinterpret_cast<const float4*>(xc + ((size_t)g * NPG + sel[r]) * 96 + c4);
    }
}

// ---------------- capsule-1 priors: 256x128 tile, 8x8/thread, swizzled LDS ----------------
// per i: out[b][c] = sum_l pooled[b,i,l] * Wc1[c>>5, i, c&31, l]
// grid: bid = i*8 + bt*4 + ct ; 512 threads
__global__ __launch_bounds__(512) void k_priors1(const float* __restrict__ pooled,
                                                 const float* __restrict__ Wc1,
                                                 float* __restrict__ priors) {
    int bid = blockIdx.x;
    int ct = bid & 3;          // 4 col tiles of 128
    int bt = (bid >> 2) & 1;   // 2 row tiles of 256
    int i = bid >> 3;          // 50
    __shared__ float As[96 * 256];  // k-major, XOR-swizzled 4-float groups
    __shared__ float Bs[96 * 128];
    int t = threadIdx.x;
    // stage As (pooled rows)
    for (int idx = t; idx < 256 * 24; idx += 512) {
        int r = idx / 24, c4 = (idx % 24) * 4;
        int b = bt * 256 + r;
        float4 v = make_float4(0.f, 0.f, 0.f, 0.f);
        if (b < NGRAPH)
            v = *reinterpret_cast<const float4*>(pooled + ((size_t)b * KP + i) * 96 + c4);
        float vv[4] = {v.x, v.y, v.z, v.w};
#pragma unroll
        for (int j = 0; j < 4; ++j) {
            int k = c4 + j;
            int gp = (r >> 2) ^ ((k >> 2) & 31);
            As[k * 256 + gp * 4 + (r & 3)] = vv[j];
        }
    }
    // stage Bs (Wc1 rows)
    for (int idx = t; idx < 128 * 24; idx += 512) {
        int c = idx / 24, c4 = (idx % 24) * 4;
        int col = ct * 128 + c;
        const float* wr = Wc1 + (((size_t)(col >> 5) * KP + i) * 32 + (col & 31)) * 96;
        float4 v = *reinterpret_cast<const float4*>(wr + c4);
        float vv[4] = {v.x, v.y, v.z, v.w};
#pragma unroll
        for (int j = 0; j < 4; ++j) {
            int k = c4 + j;
            int gp = (c >> 2) ^ ((k >> 2) & 31);
            Bs[k * 128 + gp * 4 + (c & 3)] = vv[j];
        }
    }
    __syncthreads();
    int tx = t & 15, ty = t >> 4;  // ty 0..31
    float acc[8][8];
#pragma unroll
    for (int r = 0; r < 8; ++r)
#pragma unroll
        for (int c = 0; c < 8; ++c) acc[r][c] = 0.f;
    for (int k = 0; k < 96; ++k) {
        int key = (k >> 2) & 31;
        float4 a0 = *reinterpret_cast<const float4*>(&As[k * 256 + 4 * (ty ^ key)]);
        float4 a1 = *reinterpret_cast<const float4*>(&As[k * 256 + 4 * ((32 + ty) ^ key)]);
        float4 b0 = *reinterpret_cast<const float4*>(&Bs[k * 128 + 4 * (tx ^ key)]);
        float4 b1 = *reinterpret_cast<const float4*>(&Bs[k * 128 + 4 * ((16 + tx) ^ key)]);
        float a[8] = {a0.x, a0.y, a0.z, a0.w, a1.x, a1.y, a1.z, a1.w};
        float bb[8] = {b0.x, b0.y, b0.z, b0.w, b1.x, b1.y, b1.z, b1.w};
#pragma unroll
        for (int r = 0; r < 8; ++r)
#pragma unroll
            for (int c = 0; c < 8; ++c) acc[r][c] += a[r] * bb[c];
    }
#pragma unroll
    for (int rh = 0; rh < 2; ++rh)
#pragma unroll
        for (int rr = 0; rr < 4; ++rr) {
            int b = bt * 256 + rh * 128 + ty * 4 + rr;
            if (b >= NGRAPH) continue;
#pragma unroll
            for (int ch = 0; ch < 2; ++ch) {
                int col = ct * 128 + ch * 64 + tx * 4;
                int o = col >> 5, L = col & 31;
                float4 v = make_float4(acc[rh * 4 + rr][ch * 4 + 0],
                                       acc[rh * 4 + rr][ch * 4 + 1],
                                       acc[rh * 4 + rr][ch * 4 + 2],
                                       acc[rh * 4 + rr][ch * 4 + 3]);
                *reinterpret_cast<float4*>(priors + (((size_t)b * 16 + o) * KP + i) * 32 + L) = v;
            }
        }
}

// ---------------- capsule-1 routing (per graph, all in LDS) ----------------
__global__ __launch_bounds__(256) void k_routing1(const float* __restrict__ priors_g,
                                                  float* __restrict__ v_out) {
    int b = blockIdx.x;
    __shared__ float P[16 * KP * 33];
    __shared__ float logits[16 * KP];
    __shared__ float c[16 * KP];
    __shared__ float s[16 * 32];
    __shared__ float v[16 * 32];
    __shared__ float scale[16];
    int t = threadIdx.x;
    const float* pg = priors_g + (size_t)b * (16 * KP * 32);
    for (int idx = t; idx < 16 * KP * 32; idx += 256)
        P[(idx >> 5) * 33 + (idx & 31)] = pg[idx];
    for (int idx = t; idx < 16 * KP; idx += 256) logits[idx] = 0.f;
    __syncthreads();
    for (int it = 0; it < 3; ++it) {
        if (t < KP) {
            float m = -1e30f;
            for (int o = 0; o < 16; ++o) m = fmaxf(m, logits[o * KP + t]);
            float sum = 0.f;
            for (int o = 0; o < 16; ++o) {
                float e = expf(logits[o * KP + t] - m);
                c[o * KP + t] = e;
                sum += e;
            }
            for (int o = 0; o < 16; ++o) c[o * KP + t] /= sum;
        }
        __syncthreads();
        for (int idx = t; idx < 16 * 32; idx += 256) {
            int o = idx >> 5, L = idx & 31;
            float acc = 0.f;
            for (int i = 0; i < KP; ++i) acc += c[o * KP + i] * P[(o * KP + i) * 33 + L];
            s[idx] = acc;
        }
        __syncthreads();
        if (t < 16) {
            float sq = 0.f;
            for (int L = 0; L < 32; ++L) sq += s[t * 32 + L] * s[t * 32 + L];
            scale[t] = (sq / (1.f + sq)) * (1.0f / sqrtf(sq + 1e-12f));
        }
        __syncthreads();
        for (int idx = t; idx < 16 * 32; idx += 256) v[idx] = s[idx] * scale[idx >> 5];
        __syncthreads();
        if (it < 2) {
            for (int idx = t; idx < 16 * KP; idx += 256) {
                int o = idx / KP, i = idx % KP;
                float acc = 0.f;
                for (int L = 0; L < 32; ++L) acc += P[(o * KP + i) * 33 + L] * v[o * 32 + L];
                logits[idx] += acc;
            }
            __syncthreads();
        }
    }
    for (int idx = t; idx < 16 * 32; idx += 256) v_out[(size_t)b * 512 + idx] = v[idx];
}

// ---------------- capsule-2 priors ----------------
__global__ __launch_bounds__(256) void k_priors2(const float* __restrict__ v1,
                                                 const float* __restrict__ Wc2,
                                                 float* __restrict__ priors2) {
    int b = blockIdx.x;
    __shared__ float ul[16 * 32];
    int t = threadIdx.x;
    for (int idx = t; idx < 512; idx += 256) ul[idx] = v1[(size_t)b * 512 + idx];
    __syncthreads();
    for (int idx = t; idx < NCLS * 16 * 16; idx += 256) {
        int L = idx & 15, i = (idx >> 4) & 15, o = idx >> 8;
        const float* wr = Wc2 + ((size_t)((o * 16 + i) * 16 + L)) * 32;
        const float* ur = &ul[i * 32];
        float acc = 0.f;
        for (int l = 0; l < 32; ++l) acc += wr[l] * ur[l];
        priors2[(size_t)b * (NCLS * 16 * 16) + idx] = acc;
    }
}

// ---------------- capsule-2 routing + final norms ----------------
__global__ __launch_bounds__(256) void k_routing2(const float* __restrict__ priors_g,
                                                  float* __restrict__ out) {
    int b = blockIdx.x;
    __shared__ float P[NCLS * 16 * 17];
    __shared__ float logits[NCLS * 16];
    __shared__ float c[NCLS * 16];
    __shared__ float s[NCLS * 16];
    __shared__ float v[NCLS * 16];
    __shared__ float scale[NCLS];
    int t = threadIdx.x;
    const float* pg = priors_g + (size_t)b * (NCLS * 16 * 16);
    for (int idx = t; idx < NCLS * 16 * 16; idx += 256)
        P[(idx >> 4) * 17 + (idx & 15)] = pg[idx];
    for (int idx = t; idx < NCLS * 16; idx += 256) logits[idx] = 0.f;
    __syncthreads();
    for (int it = 0; it < 3; ++it) {
        if (t < 16) {
            float m = -1e30f;
            for (int o = 0; o < NCLS; ++o) m = fmaxf(m, logits[o * 16 + t]);
            float sum = 0.f;
            for (int o = 0; o < NCLS; ++o) {
                float e = expf(logits[o * 16 + t] - m);
                c[o * 16 + t] = e;
                sum += e;
            }
            for (int o = 0; o < NCLS; ++o) c[o * 16 + t] /= sum;
        }
        __syncthreads();
        if (t < NCLS * 16) {
            int o = t >> 4, L = t & 15;
            float acc = 0.f;
            for (int i = 0; i < 16; ++i) acc += c[o * 16 + i] * P[(o * 16 + i) * 17 + L];
            s[t] = acc;
        }
        __syncthreads();
        if (t < NCLS) {
            float sq = 0.f;
            for (int L = 0; L < 16; ++L) sq += s[t * 16 + L] * s[t * 16 + L];
            scale[t] = (sq / (1.f + sq)) * (1.0f / sqrtf(sq + 1e-12f));
        }
        __syncthreads();
        if (t < NCLS * 16) v[t] = s[t] * scale[t >> 4];
        __syncthreads();
        if (it < 2) {
            if (t < NCLS * 16) {
                int o = t >> 4, i = t & 15;
                float acc = 0.f;
                for (int L = 0; L < 16; ++L) acc += P[(o * 16 + i) * 17 + L] * v[o * 16 + L];
                logits[t] += acc;
            }
            __syncthreads();
        }
    }
    if (t < NCLS) {
        float sq = 0.f;
        for (int L = 0; L < 16; ++L) sq += v[t * 16 + L] * v[t * 16 + L];
        out[(size_t)b * NCLS + t] = sqrtf(sq);
    }
}

extern "C" void kernel_launch(void* const* d_in, const int* in_sizes, int n_in,
                              void* d_out, int out_size, void* d_ws, size_t ws_size,
                              hipStream_t stream) {
    const float* x   = (const float*)d_in[0];
    const int*   ei  = (const int*)d_in[1];
    const float* W1  = (const float*)d_in[3];
    const float* b1  = (const float*)d_in[4];
    const float* W2  = (const float*)d_in[5];
    const float* b2  = (const float*)d_in[6];
    const float* W3  = (const float*)d_in[7];
    const float* b3  = (const float*)d_in[8];
    const float* Wc1 = (const float*)d_in[9];
    const float* Wc2 = (const float*)d_in[10];
    float* out = (float*)d_out;
    float* wsf = (float*)d_ws;

    const int* src = ei;
    const int* dst = ei + NEDGES;

    // ---- workspace layout (float-element offsets) ----
    float*    xc      = wsf;                        // 9,600,000
    float*    R       = wsf + 9600000;
    int*      totals  = (int*)R;                    // 196
    int*      bstart  = (int*)(R + 200);            // 197
    int*      cursor  = (int*)(R + 400);            // 196
    float*    dinv    = R + 600;                    // 100,000
    int*      offs    = (int*)(R + 100600);         // 100,001
    unsigned* csorted = (unsigned*)(R + 200608);    // 3,200,000 (dead after k_fill2)
    int*      csrc    = (int*)(R + 3400608);        // 3,200,000
    float*    h       = R + 6600608;                // 3,200,000
    // phase B: pooled aliases the dead csorted region
    float*    pooled  = R + 200608;                 // 2,400,000
    float*    pr1     = R + 9800608;                // 12,800,000
    float*    v1      = R + 22600608;               // 256,000
    float*    pr2     = R + 22856608;               // 1,280,000

    // ---- CSR build: bucketed two-level (coalesced writes) ----
    hipMemsetAsync(totals, 0, NB1 * sizeof(int), stream);
    k_hist1<<<NBLK1, 512, 0, stream>>>(src, dst, totals);
    k_scanb<<<1, 256, 0, stream>>>(totals, bstart, cursor, offs);
    k_place1<<<NBLK1, 512, 0, stream>>>(src, dst, cursor, csorted);
    k_fill2<<<NB1, 512, 0, stream>>>(bstart, csorted, csrc, offs, dinv);

    // ---- layer 1 ----
    k_matmul<<<(NNODES + 63) / 64, 256, 0, stream>>>(x, FIN, FIN, W1, dinv, h);
    k_gather<<<NNODES / 4, 256, 0, stream>>>(offs, csrc, dinv, h, b1, xc, 0);
    // ---- layer 2 ----
    k_matmul<<<(NNODES + 63) / 64, 256, 0, stream>>>(xc, 96, HID, W2, dinv, h);
    k_gather<<<NNODES / 4, 256, 0, stream>>>(offs, csrc, dinv, h, b2, xc, 32);
    // ---- layer 3 ----
    k_matmul<<<(NNODES + 63) / 64, 256, 0, stream>>>(xc + 32, 96, HID, W3, dinv, h);
    k_gather<<<NNODES / 4, 256, 0, stream>>>(offs, csrc, dinv, h, b3, xc, 64);

    // ---- sort-pool + capsules ----
    k_sortpool<<<NGRAPH, 256, 0, stream>>>(xc, pooled);
    k_priors1<<<KP * 8, 512, 0, stream>>>(pooled, Wc1, pr1);
    k_routing1<<<NGRAPH, 256, 0, stream>>>(pr1, v1);
    k_priors2<<<NGRAPH, 256, 0, stream>>>(v1, Wc2, pr2);
    k_routing2<<<NGRAPH, 256, 0, stream>>>(pr2, out);
}

// Round 6
// 425.670 us; speedup vs baseline: 10.3420x; 1.1019x over previous
//
#include <hip/hip_runtime.h>

#define NNODES 100000
#define NEDGES 3200000
#define NPG 200
#define NGRAPH 500
#define FIN 128
#define HID 32
#define KP 50
#define NCLS 10

#define NB1 196      // ceil(100000/512) dst-buckets
#define BSH 9
#define CHUNK 8192
#define NBLK1 391    // ceil(NEDGES/CHUNK)

// ---------------- level-1: bucket histogram ----------------
__global__ __launch_bounds__(512) void k_hist1(const int* __restrict__ src,
                                               const int* __restrict__ dst,
                                               int* __restrict__ totals) {
    __shared__ int hist[NB1];
    int t = threadIdx.x;
    for (int i = t; i < NB1; i += 512) hist[i] = 0;
    __syncthreads();
    int eb = blockIdx.x * CHUNK;
    for (int i = 0; i < CHUNK / 512; ++i) {
        int e = eb + t + i * 512;
        if (e < NEDGES) {
            int s = src[e], d = dst[e];
            if (s != d) atomicAdd(&hist[d >> BSH], 1);
        }
    }
    __syncthreads();
    for (int i = t; i < NB1; i += 512)
        if (hist[i]) atomicAdd(&totals[i], hist[i]);
}

// ---------------- scan bucket totals -> bstart, init cursor ----------------
__global__ __launch_bounds__(256) void k_scanb(const int* __restrict__ totals,
                                               int* __restrict__ bstart,
                                               int* __restrict__ cursor,
                                               int* __restrict__ offs) {
    __shared__ int lds[256];
    int t = threadIdx.x;
    int v = (t < NB1) ? totals[t] : 0;
    lds[t] = v;
    __syncthreads();
    for (int ofs = 1; ofs < 256; ofs <<= 1) {
        int add = (t >= ofs) ? lds[t - ofs] : 0;
        __syncthreads();
        lds[t] += add;
        __syncthreads();
    }
    if (t <= NB1) {
        int e = (t == 0) ? 0 : lds[t - 1];
        bstart[t] = e;
        if (t < NB1) cursor[t] = e;
    }
    if (t == 0) offs[NNODES] = lds[NB1 - 1];
}

// ---------------- level-1 place: LDS-binned partition, coalesced runs ----------------
__global__ __launch_bounds__(512) void k_place1(const int* __restrict__ src,
                                                const int* __restrict__ dst,
                                                int* __restrict__ cursor,
                                                unsigned* __restrict__ csorted) {
    __shared__ int hist[NB1];
    __shared__ int lstart[NB1];
    __shared__ int base[NB1];
    __shared__ int cnt2[NB1];
    __shared__ int sarr[256];
    __shared__ unsigned buf[CHUNK];
    __shared__ int dbuf[CHUNK];
    int t = threadIdx.x;
    for (int i = t; i < NB1; i += 512) { hist[i] = 0; cnt2[i] = 0; }
    __syncthreads();
    int eb = blockIdx.x * CHUNK;
    for (int i = 0; i < CHUNK / 512; ++i) {
        int e = eb + t + i * 512;
        if (e < NEDGES) {
            int s = src[e], d = dst[e];
            if (s != d) atomicAdd(&hist[d >> BSH], 1);
        }
    }
    __syncthreads();
    if (t < 256) sarr[t] = (t < NB1) ? hist[t] : 0;
    __syncthreads();
    for (int ofs = 1; ofs < 256; ofs <<= 1) {
        int add = (t < 256 && t >= ofs) ? sarr[t - ofs] : 0;
        __syncthreads();
        if (t < 256) sarr[t] += add;
        __syncthreads();
    }
    if (t < NB1) {
        lstart[t] = (t == 0) ? 0 : sarr[t - 1];
        base[t] = hist[t] ? atomicAdd(&cursor[t], hist[t]) : 0;
    }
    __syncthreads();
    for (int i = 0; i < CHUNK / 512; ++i) {
        int e = eb + t + i * 512;
        if (e < NEDGES) {
            int s = src[e], d = dst[e];
            if (s != d) {
                int bk = d >> BSH;
                int pos = atomicAdd(&cnt2[bk], 1);
                int slot = lstart[bk] + pos;
                buf[slot] = ((unsigned)s << BSH) | (unsigned)(d & 511);
                dbuf[slot] = base[bk] + pos;
            }
        }
    }
    __syncthreads();
    int nval = sarr[NB1 - 1];
    for (int j = t; j < nval; j += 512) csorted[dbuf[j]] = buf[j];
}

// ---------------- level-2: per-bucket CSR finalize (+offs, +dinv) ----------------
__global__ __launch_bounds__(512) void k_fill2(const int* __restrict__ bstart,
                                               const unsigned* __restrict__ csorted,
                                               int* __restrict__ csrc,
                                               int* __restrict__ offs,
                                               float* __restrict__ dinv) {
    __shared__ int cnt[512];
    __shared__ int loffs[512];
    __shared__ int cnt2[512];
    __shared__ int sarr[512];
    int b = blockIdx.x, t = threadIdx.x;
    cnt[t] = 0; cnt2[t] = 0;
    __syncthreads();
    int s0 = bstart[b], s1 = bstart[b + 1];
    for (int j = s0 + t; j < s1; j += 512) atomicAdd(&cnt[csorted[j] & 511], 1);
    __syncthreads();
    sarr[t] = cnt[t];
    __syncthreads();
    for (int ofs = 1; ofs < 512; ofs <<= 1) {
        int add = (t >= ofs) ? sarr[t - ofs] : 0;
        __syncthreads();
        sarr[t] += add;
        __syncthreads();
    }
    loffs[t] = sarr[t] - cnt[t];  // exclusive
    __syncthreads();
    int n = b * 512 + t;
    if (n < NNODES) {
        offs[n] = s0 + loffs[t];
        dinv[n] = rsqrtf((float)cnt[t] + 1.0f);
    }
    for (int j = s0 + t; j < s1; j += 512) {
        unsigned p = csorted[j];
        int d = p & 511;
        int pos = atomicAdd(&cnt2[d], 1);
        csrc[s0 + loffs[d] + pos] = (int)(p >> BSH);
    }
}

// ---------------- hw = (X @ W) * dinv : 64 rows/block, 8 rows/thread ----------------
__global__ __launch_bounds__(256) void k_matmul(const float* __restrict__ X, int ldx, int K,
                                                const float* __restrict__ W,
                                                const float* __restrict__ dinv,
                                                float* __restrict__ h) {
    __shared__ float Wl[FIN * HID];
    __shared__ float Xl[64 * FIN];
    int t = threadIdx.x;
    for (int idx = t; idx < K * HID; idx += 256) Wl[idx] = W[idx];
    int n0 = blockIdx.x * 64;
    int ng = 64 * K / 4;
    for (int idx = t; idx < ng; idx += 256) {
        int r = (idx * 4) / K, c = (idx * 4) % K;
        float4 v = make_float4(0.f, 0.f, 0.f, 0.f);
        if (n0 + r < NNODES)
            v = *reinterpret_cast<const float4*>(X + (size_t)(n0 + r) * ldx + c);
        *reinterpret_cast<float4*>(&Xl[r * K + c]) = v;
    }
    __syncthreads();
    int j = t & 31, g = t >> 5;
    const float* xr = &Xl[(g * 8) * K];
    float a0 = 0, a1 = 0, a2 = 0, a3 = 0, a4 = 0, a5 = 0, a6 = 0, a7 = 0;
    for (int k = 0; k < K; ++k) {
        float w = Wl[k * HID + j];
        a0 += w * xr[0 * K + k];
        a1 += w * xr[1 * K + k];
        a2 += w * xr[2 * K + k];
        a3 += w * xr[3 * K + k];
        a4 += w * xr[4 * K + k];
        a5 += w * xr[5 * K + k];
        a6 += w * xr[6 * K + k];
        a7 += w * xr[7 * K + k];
    }
    int r0 = n0 + g * 8;
    float av[8] = {a0, a1, a2, a3, a4, a5, a6, a7};
    for (int q = 0; q < 8; ++q)
        if (r0 + q < NNODES) h[(size_t)(r0 + q) * HID + j] = av[q] * dinv[r0 + q];
}

// ---------------- gather: 32 edges/wave-iter (4x unrolled), clamp+mask tail ----------------
__global__ __launch_bounds__(256) void k_gather(const int* __restrict__ offs,
                                                const int* __restrict__ csrc,
                                                const float* __restrict__ dinv,
                                                const float* __restrict__ hw,
                                                const float* __restrict__ bias,
                                                float* __restrict__ xc, int coloff) {
    int t = threadIdx.x;
    int n = blockIdx.x * 4 + (t >> 6);
    int lane = t & 63;
    int g = lane >> 3;   // edge slot 0..7
    int q = lane & 7;    // channel quad 0..7
    int beg = offs[n], end = offs[n + 1];
    int last = end - 1;
    float4 acc = make_float4(0.f, 0.f, 0.f, 0.f);
    for (int e0 = beg + g; e0 < end; e0 += 32) {
        int eB = e0 + 8, eC = e0 + 16, eD = e0 + 24;
        float mB = (eB <= last) ? 1.f : 0.f;
        float mC = (eC <= last) ? 1.f : 0.f;
        float mD = (eD <= last) ? 1.f : 0.f;
        int sA = csrc[e0];
        int sB = csrc[min(eB, last)];
        int sC = csrc[min(eC, last)];
        int sD = csrc[min(eD, last)];
        float4 hA = *reinterpret_cast<const float4*>(hw + (size_t)sA * HID + q * 4);
        float4 hB = *reinterpret_cast<const float4*>(hw + (size_t)sB * HID + q * 4);
        float4 hC = *reinterpret_cast<const float4*>(hw + (size_t)sC * HID + q * 4);
        float4 hD = *reinterpret_cast<const float4*>(hw + (size_t)sD * HID + q * 4);
        acc.x += hA.x; acc.y += hA.y; acc.z += hA.z; acc.w += hA.w;
        acc.x += mB * hB.x; acc.y += mB * hB.y; acc.z += mB * hB.z; acc.w += mB * hB.w;
        acc.x += mC * hC.x; acc.y += mC * hC.y; acc.z += mC * hC.z; acc.w += mC * hC.w;
        acc.x += mD * hD.x; acc.y += mD * hD.y; acc.z += mD * hD.z; acc.w += mD * hD.w;
    }
    for (int m = 8; m <= 32; m <<= 1) {
        acc.x += __shfl_xor(acc.x, m, 64);
        acc.y += __shfl_xor(acc.y, m, 64);
        acc.z += __shfl_xor(acc.z, m, 64);
        acc.w += __shfl_xor(acc.w, m, 64);
    }
    if (g == 0) {
        float di = dinv[n];
        float4 hv = *reinterpret_cast<const float4*>(hw + (size_t)n * HID + q * 4);
        float4 bv = *reinterpret_cast<const float4*>(bias + q * 4);
        float4 v;
        v.x = tanhf(di * (acc.x + hv.x) + bv.x);
        v.y = tanhf(di * (acc.y + hv.y) + bv.y);
        v.z = tanhf(di * (acc.z + hv.z) + bv.z);
        v.w = tanhf(di * (acc.w + hv.w) + bv.w);
        *reinterpret_cast<float4*>(xc + (size_t)n * 96 + coloff + q * 4) = v;
    }
}

// ---------------- stable top-50 sort-pool per graph ----------------
__global__ __launch_bounds__(256) void k_sortpool(const float* __restrict__ xc,
                                                  float* __restrict__ pooled) {
    int g = blockIdx.x;
    __shared__ float vals[NPG];
    __shared__ int sel[KP];
    int t = threadIdx.x;
    if (t < NPG) vals[t] = xc[((size_t)g * NPG + t) * 96 + 95];
    __syncthreads();
    if (t < NPG) {
        float v = vals[t];
        int r = 0;
        for (int k = 0; k < NPG; ++k) {
            float vk = vals[k];
            r += (vk > v) || (vk == v && k < t);
        }
        if (r < KP) sel[r] = t;
    }
    __syncthreads();
    for (int idx = t; idx < KP * 24; idx += 256) {
        int r = idx / 24, c4 = (idx % 24) * 4;
        *reinterpret_cast<float4*>(pooled + (size_t)g * KP * 96 + r * 96 + c4) =
            *reinterpret_cast<const float4*>(xc + ((size_t)g * NPG + sel[r]) * 96 + c4);
    }
}

// ---------------- capsule-1 priors: 256x128 tile, 8x8/thread, swizzled LDS ----------------
__global__ __launch_bounds__(512) void k_priors1(const float* __restrict__ pooled,
                                                 const float* __restrict__ Wc1,
                                                 float* __restrict__ priors) {
    int bid = blockIdx.x;
    int ct = bid & 3;          // 4 col tiles of 128
    int bt = (bid >> 2) & 1;   // 2 row tiles of 256
    int i = bid >> 3;          // 50
    __shared__ float As[96 * 256];  // k-major, XOR-swizzled 4-float groups
    __shared__ float Bs[96 * 128];
    int t = threadIdx.x;
    for (int idx = t; idx < 256 * 24; idx += 512) {
        int r = idx / 24, c4 = (idx % 24) * 4;
        int b = bt * 256 + r;
        float4 v = make_float4(0.f, 0.f, 0.f, 0.f);
        if (b < NGRAPH)
            v = *reinterpret_cast<const float4*>(pooled + ((size_t)b * KP + i) * 96 + c4);
        float vv[4] = {v.x, v.y, v.z, v.w};
#pragma unroll
        for (int j = 0; j < 4; ++j) {
            int k = c4 + j;
            int gp = (r >> 2) ^ ((k >> 2) & 31);
            As[k * 256 + gp * 4 + (r & 3)] = vv[j];
        }
    }
    for (int idx = t; idx < 128 * 24; idx += 512) {
        int c = idx / 24, c4 = (idx % 24) * 4;
        int col = ct * 128 + c;
        const float* wr = Wc1 + (((size_t)(col >> 5) * KP + i) * 32 + (col & 31)) * 96;
        float4 v = *reinterpret_cast<const float4*>(wr + c4);
        float vv[4] = {v.x, v.y, v.z, v.w};
#pragma unroll
        for (int j = 0; j < 4; ++j) {
            int k = c4 + j;
            int gp = (c >> 2) ^ ((k >> 2) & 31);
            Bs[k * 128 + gp * 4 + (c & 3)] = vv[j];
        }
    }
    __syncthreads();
    int tx = t & 15, ty = t >> 4;  // ty 0..31
    float acc[8][8];
#pragma unroll
    for (int r = 0; r < 8; ++r)
#pragma unroll
        for (int c = 0; c < 8; ++c) acc[r][c] = 0.f;
    for (int k = 0; k < 96; ++k) {
        int key = (k >> 2) & 31;
        float4 a0 = *reinterpret_cast<const float4*>(&As[k * 256 + 4 * (ty ^ key)]);
        float4 a1 = *reinterpret_cast<const float4*>(&As[k * 256 + 4 * ((32 + ty) ^ key)]);
        float4 b0 = *reinterpret_cast<const float4*>(&Bs[k * 128 + 4 * (tx ^ key)]);
        float4 b1 = *reinterpret_cast<const float4*>(&Bs[k * 128 + 4 * ((16 + tx) ^ key)]);
        float a[8] = {a0.x, a0.y, a0.z, a0.w, a1.x, a1.y, a1.z, a1.w};
        float bb[8] = {b0.x, b0.y, b0.z, b0.w, b1.x, b1.y, b1.z, b1.w};
#pragma unroll
        for (int r = 0; r < 8; ++r)
#pragma unroll
            for (int c = 0; c < 8; ++c) acc[r][c] += a[r] * bb[c];
    }
#pragma unroll
    for (int rh = 0; rh < 2; ++rh)
#pragma unroll
        for (int rr = 0; rr < 4; ++rr) {
            int b = bt * 256 + rh * 128 + ty * 4 + rr;
            if (b >= NGRAPH) continue;
#pragma unroll
            for (int ch = 0; ch < 2; ++ch) {
                int col = ct * 128 + ch * 64 + tx * 4;
                int o = col >> 5, L = col & 31;
                float4 v = make_float4(acc[rh * 4 + rr][ch * 4 + 0],
                                       acc[rh * 4 + rr][ch * 4 + 1],
                                       acc[rh * 4 + rr][ch * 4 + 2],
                                       acc[rh * 4 + rr][ch * 4 + 3]);
                *reinterpret_cast<float4*>(priors + (((size_t)b * 16 + o) * KP + i) * 32 + L) = v;
            }
        }
}

// ---------------- capsule-1 routing (per graph, all in LDS) ----------------
__global__ __launch_bounds__(256) void k_routing1(const float* __restrict__ priors_g,
                                                  float* __restrict__ v_out) {
    int b = blockIdx.x;
    __shared__ float P[16 * KP * 33];
    __shared__ float logits[16 * KP];
    __shared__ float c[16 * KP];
    __shared__ float s[16 * 32];
    __shared__ float v[16 * 32];
    __shared__ float scale[16];
    int t = threadIdx.x;
    const float* pg = priors_g + (size_t)b * (16 * KP * 32);
    for (int idx = t; idx < 16 * KP * 32; idx += 256)
        P[(idx >> 5) * 33 + (idx & 31)] = pg[idx];
    for (int idx = t; idx < 16 * KP; idx += 256) logits[idx] = 0.f;
    __syncthreads();
    for (int it = 0; it < 3; ++it) {
        if (t < KP) {
            float m = -1e30f;
            for (int o = 0; o < 16; ++o) m = fmaxf(m, logits[o * KP + t]);
            float sum = 0.f;
            for (int o = 0; o < 16; ++o) {
                float e = expf(logits[o * KP + t] - m);
                c[o * KP + t] = e;
                sum += e;
            }
            for (int o = 0; o < 16; ++o) c[o * KP + t] /= sum;
        }
        __syncthreads();
        for (int idx = t; idx < 16 * 32; idx += 256) {
            int o = idx >> 5, L = idx & 31;
            float acc = 0.f;
            for (int i = 0; i < KP; ++i) acc += c[o * KP + i] * P[(o * KP + i) * 33 + L];
            s[idx] = acc;
        }
        __syncthreads();
        if (t < 16) {
            float sq = 0.f;
            for (int L = 0; L < 32; ++L) sq += s[t * 32 + L] * s[t * 32 + L];
            scale[t] = (sq / (1.f + sq)) * (1.0f / sqrtf(sq + 1e-12f));
        }
        __syncthreads();
        for (int idx = t; idx < 16 * 32; idx += 256) v[idx] = s[idx] * scale[idx >> 5];
        __syncthreads();
        if (it < 2) {
            for (int idx = t; idx < 16 * KP; idx += 256) {
                int o = idx / KP, i = idx % KP;
                float acc = 0.f;
                for (int L = 0; L < 32; ++L) acc += P[(o * KP + i) * 33 + L] * v[o * 32 + L];
                logits[idx] += acc;
            }
            __syncthreads();
        }
    }
    for (int idx = t; idx < 16 * 32; idx += 256) v_out[(size_t)b * 512 + idx] = v[idx];
}

// ---------------- capsule-2 priors ----------------
__global__ __launch_bounds__(256) void k_priors2(const float* __restrict__ v1,
                                                 const float* __restrict__ Wc2,
                                                 float* __restrict__ priors2) {
    int b = blockIdx.x;
    __shared__ float ul[16 * 32];
    int t = threadIdx.x;
    for (int idx = t; idx < 512; idx += 256) ul[idx] = v1[(size_t)b * 512 + idx];
    __syncthreads();
    for (int idx = t; idx < NCLS * 16 * 16; idx += 256) {
        int L = idx & 15, i = (idx >> 4) & 15, o = idx >> 8;
        const float* wr = Wc2 + ((size_t)((o * 16 + i) * 16 + L)) * 32;
        const float* ur = &ul[i * 32];
        float acc = 0.f;
        for (int l = 0; l < 32; ++l) acc += wr[l] * ur[l];
        priors2[(size_t)b * (NCLS * 16 * 16) + idx] = acc;
    }
}

// ---------------- capsule-2 routing + final norms ----------------
__global__ __launch_bounds__(256) void k_routing2(const float* __restrict__ priors_g,
                                                  float* __restrict__ out) {
    int b = blockIdx.x;
    __shared__ float P[NCLS * 16 * 17];
    __shared__ float logits[NCLS * 16];
    __shared__ float c[NCLS * 16];
    __shared__ float s[NCLS * 16];
    __shared__ float v[NCLS * 16];
    __shared__ float scale[NCLS];
    int t = threadIdx.x;
    const float* pg = priors_g + (size_t)b * (NCLS * 16 * 16);
    for (int idx = t; idx < NCLS * 16 * 16; idx += 256)
        P[(idx >> 4) * 17 + (idx & 15)] = pg[idx];
    for (int idx = t; idx < NCLS * 16; idx += 256) logits[idx] = 0.f;
    __syncthreads();
    for (int it = 0; it < 3; ++it) {
        if (t < 16) {
            float m = -1e30f;
            for (int o = 0; o < NCLS; ++o) m = fmaxf(m, logits[o * 16 + t]);
            float sum = 0.f;
            for (int o = 0; o < NCLS; ++o) {
                float e = expf(logits[o * 16 + t] - m);
                c[o * 16 + t] = e;
                sum += e;
            }
            for (int o = 0; o < NCLS; ++o) c[o * 16 + t] /= sum;
        }
        __syncthreads();
        if (t < NCLS * 16) {
            int o = t >> 4, L = t & 15;
            float acc = 0.f;
            for (int i = 0; i < 16; ++i) acc += c[o * 16 + i] * P[(o * 16 + i) * 17 + L];
            s[t] = acc;
        }
        __syncthreads();
        if (t < NCLS) {
            float sq = 0.f;
            for (int L = 0; L < 16; ++L) sq += s[t * 16 + L] * s[t * 16 + L];
            scale[t] = (sq / (1.f + sq)) * (1.0f / sqrtf(sq + 1e-12f));
        }
        __syncthreads();
        if (t < NCLS * 16) v[t] = s[t] * scale[t >> 4];
        __syncthreads();
        if (it < 2) {
            if (t < NCLS * 16) {
                int o = t >> 4, i = t & 15;
                float acc = 0.f;
                for (int L = 0; L < 16; ++L) acc += P[(o * 16 + i) * 17 + L] * v[o * 16 + L];
                logits[t] += acc;
            }
            __syncthreads();
        }
    }
    if (t < NCLS) {
        float sq = 0.f;
        for (int L = 0; L < 16; ++L) sq += v[t * 16 + L] * v[t * 16 + L];
        out[(size_t)b * NCLS + t] = sqrtf(sq);
    }
}

extern "C" void kernel_launch(void* const* d_in, const int* in_sizes, int n_in,
                              void* d_out, int out_size, void* d_ws, size_t ws_size,
                              hipStream_t stream) {
    const float* x   = (const float*)d_in[0];
    const int*   ei  = (const int*)d_in[1];
    const float* W1  = (const float*)d_in[3];
    const float* b1  = (const float*)d_in[4];
    const float* W2  = (const float*)d_in[5];
    const float* b2  = (const float*)d_in[6];
    const float* W3  = (const float*)d_in[7];
    const float* b3  = (const float*)d_in[8];
    const float* Wc1 = (const float*)d_in[9];
    const float* Wc2 = (const float*)d_in[10];
    float* out = (float*)d_out;
    float* wsf = (float*)d_ws;

    const int* src = ei;
    const int* dst = ei + NEDGES;

    // ---- workspace layout (float-element offsets) ----
    float*    xc      = wsf;                        // 9,600,000
    float*    R       = wsf + 9600000;
    int*      totals  = (int*)R;                    // 196
    int*      bstart  = (int*)(R + 200);            // 197
    int*      cursor  = (int*)(R + 400);            // 196
    float*    dinv    = R + 600;                    // 100,000
    int*      offs    = (int*)(R + 100600);         // 100,001
    unsigned* csorted = (unsigned*)(R + 200608);    // 3,200,000 (dead after k_fill2)
    int*      csrc    = (int*)(R + 3400608);        // 3,200,000
    float*    h       = R + 6600608;                // 3,200,000
    // phase B: pooled aliases the dead csorted region
    float*    pooled  = R + 200608;                 // 2,400,000
    float*    pr1     = R + 9800608;                // 12,800,000
    float*    v1      = R + 22600608;               // 256,000
    float*    pr2     = R + 22856608;               // 1,280,000

    // ---- CSR build: bucketed two-level (coalesced writes) ----
    hipMemsetAsync(totals, 0, NB1 * sizeof(int), stream);
    k_hist1<<<NBLK1, 512, 0, stream>>>(src, dst, totals);
    k_scanb<<<1, 256, 0, stream>>>(totals, bstart, cursor, offs);
    k_place1<<<NBLK1, 512, 0, stream>>>(src, dst, cursor, csorted);
    k_fill2<<<NB1, 512, 0, stream>>>(bstart, csorted, csrc, offs, dinv);

    // ---- layer 1 ----
    k_matmul<<<(NNODES + 63) / 64, 256, 0, stream>>>(x, FIN, FIN, W1, dinv, h);
    k_gather<<<NNODES / 4, 256, 0, stream>>>(offs, csrc, dinv, h, b1, xc, 0);
    // ---- layer 2 ----
    k_matmul<<<(NNODES + 63) / 64, 256, 0, stream>>>(xc, 96, HID, W2, dinv, h);
    k_gather<<<NNODES / 4, 256, 0, stream>>>(offs, csrc, dinv, h, b2, xc, 32);
    // ---- layer 3 ----
    k_matmul<<<(NNODES + 63) / 64, 256, 0, stream>>>(xc + 32, 96, HID, W3, dinv, h);
    k_gather<<<NNODES / 4, 256, 0, stream>>>(offs, csrc, dinv, h, b3, xc, 64);

    // ---- sort-pool + capsules ----
    k_sortpool<<<NGRAPH, 256, 0, stream>>>(xc, pooled);
    k_priors1<<<KP * 8, 512, 0, stream>>>(pooled, Wc1, pr1);
    k_routing1<<<NGRAPH, 256, 0, stream>>>(pr1, v1);
    k_priors2<<<NGRAPH, 256, 0, stream>>>(v1, Wc2, pr2);
    k_routing2<<<NGRAPH, 256, 0, stream>>>(pr2, out);
}

// Round 7
// 416.720 us; speedup vs baseline: 10.5642x; 1.0215x over previous
//
#include <hip/hip_runtime.h>

#define NNODES 100000
#define NEDGES 3200000
#define NPG 200
#define NGRAPH 500
#define FIN 128
#define HID 32
#define KP 50
#define NCLS 10

#define NB1 196      // ceil(100000/512) dst-buckets
#define BSH 9
#define CHUNK 8192
#define NBLK1 391    // ceil(NEDGES/CHUNK)

// ---------------- level-1: bucket histogram ----------------
__global__ __launch_bounds__(512) void k_hist1(const int* __restrict__ src,
                                               const int* __restrict__ dst,
                                               int* __restrict__ totals) {
    __shared__ int hist[NB1];
    int t = threadIdx.x;
    for (int i = t; i < NB1; i += 512) hist[i] = 0;
    __syncthreads();
    int eb = blockIdx.x * CHUNK;
    for (int i = 0; i < CHUNK / 512; ++i) {
        int e = eb + t + i * 512;
        if (e < NEDGES) {
            int s = src[e], d = dst[e];
            if (s != d) atomicAdd(&hist[d >> BSH], 1);
        }
    }
    __syncthreads();
    for (int i = t; i < NB1; i += 512)
        if (hist[i]) atomicAdd(&totals[i], hist[i]);
}

// ---------------- scan bucket totals -> bstart, init cursor ----------------
__global__ __launch_bounds__(256) void k_scanb(const int* __restrict__ totals,
                                               int* __restrict__ bstart,
                                               int* __restrict__ cursor,
                                               int* __restrict__ offs) {
    __shared__ int lds[256];
    int t = threadIdx.x;
    int v = (t < NB1) ? totals[t] : 0;
    lds[t] = v;
    __syncthreads();
    for (int ofs = 1; ofs < 256; ofs <<= 1) {
        int add = (t >= ofs) ? lds[t - ofs] : 0;
        __syncthreads();
        lds[t] += add;
        __syncthreads();
    }
    if (t <= NB1) {
        int e = (t == 0) ? 0 : lds[t - 1];
        bstart[t] = e;
        if (t < NB1) cursor[t] = e;
    }
    if (t == 0) offs[NNODES] = lds[NB1 - 1];
}

// ---------------- level-1 place: LDS-binned partition, coalesced runs ----------------
__global__ __launch_bounds__(512) void k_place1(const int* __restrict__ src,
                                                const int* __restrict__ dst,
                                                int* __restrict__ cursor,
                                                unsigned* __restrict__ csorted) {
    __shared__ int hist[NB1];
    __shared__ int lstart[NB1];
    __shared__ int base[NB1];
    __shared__ int cnt2[NB1];
    __shared__ int sarr[256];
    __shared__ unsigned buf[CHUNK];
    __shared__ int dbuf[CHUNK];
    int t = threadIdx.x;
    for (int i = t; i < NB1; i += 512) { hist[i] = 0; cnt2[i] = 0; }
    __syncthreads();
    int eb = blockIdx.x * CHUNK;
    for (int i = 0; i < CHUNK / 512; ++i) {
        int e = eb + t + i * 512;
        if (e < NEDGES) {
            int s = src[e], d = dst[e];
            if (s != d) atomicAdd(&hist[d >> BSH], 1);
        }
    }
    __syncthreads();
    if (t < 256) sarr[t] = (t < NB1) ? hist[t] : 0;
    __syncthreads();
    for (int ofs = 1; ofs < 256; ofs <<= 1) {
        int add = (t < 256 && t >= ofs) ? sarr[t - ofs] : 0;
        __syncthreads();
        if (t < 256) sarr[t] += add;
        __syncthreads();
    }
    if (t < NB1) {
        lstart[t] = (t == 0) ? 0 : sarr[t - 1];
        base[t] = hist[t] ? atomicAdd(&cursor[t], hist[t]) : 0;
    }
    __syncthreads();
    for (int i = 0; i < CHUNK / 512; ++i) {
        int e = eb + t + i * 512;
        if (e < NEDGES) {
            int s = src[e], d = dst[e];
            if (s != d) {
                int bk = d >> BSH;
                int pos = atomicAdd(&cnt2[bk], 1);
                int slot = lstart[bk] + pos;
                buf[slot] = ((unsigned)s << BSH) | (unsigned)(d & 511);
                dbuf[slot] = base[bk] + pos;
            }
        }
    }
    __syncthreads();
    int nval = sarr[NB1 - 1];
    for (int j = t; j < nval; j += 512) csorted[dbuf[j]] = buf[j];
}

// ---------------- level-2: per-bucket CSR finalize (+offs, +dinv) ----------------
__global__ __launch_bounds__(512) void k_fill2(const int* __restrict__ bstart,
                                               const unsigned* __restrict__ csorted,
                                               int* __restrict__ csrc,
                                               int* __restrict__ offs,
                                               float* __restrict__ dinv) {
    __shared__ int cnt[512];
    __shared__ int loffs[512];
    __shared__ int cnt2[512];
    __shared__ int sarr[512];
    int b = blockIdx.x, t = threadIdx.x;
    cnt[t] = 0; cnt2[t] = 0;
    __syncthreads();
    int s0 = bstart[b], s1 = bstart[b + 1];
    for (int j = s0 + t; j < s1; j += 512) atomicAdd(&cnt[csorted[j] & 511], 1);
    __syncthreads();
    sarr[t] = cnt[t];
    __syncthreads();
    for (int ofs = 1; ofs < 512; ofs <<= 1) {
        int add = (t >= ofs) ? sarr[t - ofs] : 0;
        __syncthreads();
        sarr[t] += add;
        __syncthreads();
    }
    loffs[t] = sarr[t] - cnt[t];  // exclusive
    __syncthreads();
    int n = b * 512 + t;
    if (n < NNODES) {
        offs[n] = s0 + loffs[t];
        dinv[n] = rsqrtf((float)cnt[t] + 1.0f);
    }
    for (int j = s0 + t; j < s1; j += 512) {
        unsigned p = csorted[j];
        int d = p & 511;
        int pos = atomicAdd(&cnt2[d], 1);
        csrc[s0 + loffs[d] + pos] = (int)(p >> BSH);
    }
}

// ---------------- hw = (X @ W) * dinv : 64 rows/block, 8 rows/thread ----------------
__global__ __launch_bounds__(256) void k_matmul(const float* __restrict__ X, int ldx, int K,
                                                const float* __restrict__ W,
                                                const float* __restrict__ dinv,
                                                float* __restrict__ h) {
    __shared__ float Wl[FIN * HID];
    __shared__ float Xl[64 * FIN];
    int t = threadIdx.x;
    for (int idx = t; idx < K * HID; idx += 256) Wl[idx] = W[idx];
    int n0 = blockIdx.x * 64;
    int ng = 64 * K / 4;
    for (int idx = t; idx < ng; idx += 256) {
        int r = (idx * 4) / K, c = (idx * 4) % K;
        float4 v = make_float4(0.f, 0.f, 0.f, 0.f);
        if (n0 + r < NNODES)
            v = *reinterpret_cast<const float4*>(X + (size_t)(n0 + r) * ldx + c);
        *reinterpret_cast<float4*>(&Xl[r * K + c]) = v;
    }
    __syncthreads();
    int j = t & 31, g = t >> 5;
    const float* xr = &Xl[(g * 8) * K];
    float a0 = 0, a1 = 0, a2 = 0, a3 = 0, a4 = 0, a5 = 0, a6 = 0, a7 = 0;
    for (int k = 0; k < K; ++k) {
        float w = Wl[k * HID + j];
        a0 += w * xr[0 * K + k];
        a1 += w * xr[1 * K + k];
        a2 += w * xr[2 * K + k];
        a3 += w * xr[3 * K + k];
        a4 += w * xr[4 * K + k];
        a5 += w * xr[5 * K + k];
        a6 += w * xr[6 * K + k];
        a7 += w * xr[7 * K + k];
    }
    int r0 = n0 + g * 8;
    float av[8] = {a0, a1, a2, a3, a4, a5, a6, a7};
    for (int q = 0; q < 8; ++q)
        if (r0 + q < NNODES) h[(size_t)(r0 + q) * HID + j] = av[q] * dinv[r0 + q];
}

// ---------------- gather: 32 edges/wave-iter (4x unrolled), clamp+mask tail ----------------
__global__ __launch_bounds__(256) void k_gather(const int* __restrict__ offs,
                                                const int* __restrict__ csrc,
                                                const float* __restrict__ dinv,
                                                const float* __restrict__ hw,
                                                const float* __restrict__ bias,
                                                float* __restrict__ xc, int coloff) {
    int t = threadIdx.x;
    int n = blockIdx.x * 4 + (t >> 6);
    int lane = t & 63;
    int g = lane >> 3;   // edge slot 0..7
    int q = lane & 7;    // channel quad 0..7
    int beg = offs[n], end = offs[n + 1];
    int last = end - 1;
    float4 acc = make_float4(0.f, 0.f, 0.f, 0.f);
    for (int e0 = beg + g; e0 < end; e0 += 32) {
        int eB = e0 + 8, eC = e0 + 16, eD = e0 + 24;
        float mB = (eB <= last) ? 1.f : 0.f;
        float mC = (eC <= last) ? 1.f : 0.f;
        float mD = (eD <= last) ? 1.f : 0.f;
        int sA = csrc[e0];
        int sB = csrc[min(eB, last)];
        int sC = csrc[min(eC, last)];
        int sD = csrc[min(eD, last)];
        float4 hA = *reinterpret_cast<const float4*>(hw + (size_t)sA * HID + q * 4);
        float4 hB = *reinterpret_cast<const float4*>(hw + (size_t)sB * HID + q * 4);
        float4 hC = *reinterpret_cast<const float4*>(hw + (size_t)sC * HID + q * 4);
        float4 hD = *reinterpret_cast<const float4*>(hw + (size_t)sD * HID + q * 4);
        acc.x += hA.x; acc.y += hA.y; acc.z += hA.z; acc.w += hA.w;
        acc.x += mB * hB.x; acc.y += mB * hB.y; acc.z += mB * hB.z; acc.w += mB * hB.w;
        acc.x += mC * hC.x; acc.y += mC * hC.y; acc.z += mC * hC.z; acc.w += mC * hC.w;
        acc.x += mD * hD.x; acc.y += mD * hD.y; acc.z += mD * hD.z; acc.w += mD * hD.w;
    }
    for (int m = 8; m <= 32; m <<= 1) {
        acc.x += __shfl_xor(acc.x, m, 64);
        acc.y += __shfl_xor(acc.y, m, 64);
        acc.z += __shfl_xor(acc.z, m, 64);
        acc.w += __shfl_xor(acc.w, m, 64);
    }
    if (g == 0) {
        float di = dinv[n];
        float4 hv = *reinterpret_cast<const float4*>(hw + (size_t)n * HID + q * 4);
        float4 bv = *reinterpret_cast<const float4*>(bias + q * 4);
        float4 v;
        v.x = tanhf(di * (acc.x + hv.x) + bv.x);
        v.y = tanhf(di * (acc.y + hv.y) + bv.y);
        v.z = tanhf(di * (acc.z + hv.z) + bv.z);
        v.w = tanhf(di * (acc.w + hv.w) + bv.w);
        *reinterpret_cast<float4*>(xc + (size_t)n * 96 + coloff + q * 4) = v;
    }
}

// ---------------- stable top-50 sort-pool per graph ----------------
__global__ __launch_bounds__(256) void k_sortpool(const float* __restrict__ xc,
                                                  float* __restrict__ pooled) {
    int g = blockIdx.x;
    __shared__ float vals[NPG];
    __shared__ int sel[KP];
    int t = threadIdx.x;
    if (t < NPG) vals[t] = xc[((size_t)g * NPG + t) * 96 + 95];
    __syncthreads();
    if (t < NPG) {
        float v = vals[t];
        int r = 0;
        for (int k = 0; k < NPG; ++k) {
            float vk = vals[k];
            r += (vk > v) || (vk == v && k < t);
        }
        if (r < KP) sel[r] = t;
    }
    __syncthreads();
    for (int idx = t; idx < KP * 24; idx += 256) {
        int r = idx / 24, c4 = (idx % 24) * 4;
        *reinterpret_cast<float4*>(pooled + (size_t)g * KP * 96 + r * 96 + c4) =
            *reinterpret_cast<const float4*>(xc + ((size_t)g * NPG + sel[r]) * 96 + c4);
    }
}

// ---------------- capsule-1 priors: 256x128 tile, 8x8/thread, K-split LDS ----------------
// per i: out[b][c] = sum_l pooled[b,i,l] * Wc1[c>>5, i, c&31, l]
// grid: bid = i*8 + bt*4 + ct ; 512 threads; K=96 staged in 2 halves of 48
__global__ __launch_bounds__(512) void k_priors1(const float* __restrict__ pooled,
                                                 const float* __restrict__ Wc1,
                                                 float* __restrict__ priors) {
    int bid = blockIdx.x;
    int ct = bid & 3;          // 4 col tiles of 128
    int bt = (bid >> 2) & 1;   // 2 row tiles of 256
    int i = bid >> 3;          // 50
    __shared__ float As[48 * 256];  // 48 KiB, k-major, XOR-swizzled 4-float groups
    __shared__ float Bs[48 * 128];  // 24 KiB  -> total 73.7 KiB => 2 blocks/CU
    int t = threadIdx.x;
    int tx = t & 15, ty = t >> 4;  // ty 0..31
    float acc[8][8];
#pragma unroll
    for (int r = 0; r < 8; ++r)
#pragma unroll
        for (int c = 0; c < 8; ++c) acc[r][c] = 0.f;

    for (int kh = 0; kh < 2; ++kh) {
        int kbase = kh * 48;
        __syncthreads();  // protect previous half's reads before overwrite
        // stage As (pooled rows), 12 float4 per row
        for (int idx = t; idx < 256 * 12; idx += 512) {
            int r = idx / 12, c4 = (idx % 12) * 4;
            int b = bt * 256 + r;
            float4 v = make_float4(0.f, 0.f, 0.f, 0.f);
            if (b < NGRAPH)
                v = *reinterpret_cast<const float4*>(pooled + ((size_t)b * KP + i) * 96 + kbase + c4);
            float vv[4] = {v.x, v.y, v.z, v.w};
#pragma unroll
            for (int j = 0; j < 4; ++j) {
                int k = c4 + j;
                int gp = (r >> 2) ^ ((k >> 2) & 31);
                As[k * 256 + gp * 4 + (r & 3)] = vv[j];
            }
        }
        // stage Bs (Wc1 rows)
        for (int idx = t; idx < 128 * 12; idx += 512) {
            int c = idx / 12, c4 = (idx % 12) * 4;
            int col = ct * 128 + c;
            const float* wr = Wc1 + (((size_t)(col >> 5) * KP + i) * 32 + (col & 31)) * 96;
            float4 v = *reinterpret_cast<const float4*>(wr + kbase + c4);
            float vv[4] = {v.x, v.y, v.z, v.w};
#pragma unroll
            for (int j = 0; j < 4; ++j) {
                int k = c4 + j;
                int gp = (c >> 2) ^ ((k >> 2) & 31);
                Bs[k * 128 + gp * 4 + (c & 3)] = vv[j];
            }
        }
        __syncthreads();
        for (int k = 0; k < 48; ++k) {
            int key = (k >> 2) & 31;
            float4 a0 = *reinterpret_cast<const float4*>(&As[k * 256 + 4 * (ty ^ key)]);
            float4 a1 = *reinterpret_cast<const float4*>(&As[k * 256 + 4 * ((32 + ty) ^ key)]);
            float4 b0 = *reinterpret_cast<const float4*>(&Bs[k * 128 + 4 * (tx ^ key)]);
            float4 b1 = *reinterpret_cast<const float4*>(&Bs[k * 128 + 4 * ((16 + tx) ^ key)]);
            float a[8] = {a0.x, a0.y, a0.z, a0.w, a1.x, a1.y, a1.z, a1.w};
            float bb[8] = {b0.x, b0.y, b0.z, b0.w, b1.x, b1.y, b1.z, b1.w};
#pragma unroll
            for (int r = 0; r < 8; ++r)
#pragma unroll
                for (int c = 0; c < 8; ++c) acc[r][c] += a[r] * bb[c];
        }
    }
#pragma unroll
    for (int rh = 0; rh < 2; ++rh)
#pragma unroll
        for (int rr = 0; rr < 4; ++rr) {
            int b = bt * 256 + rh * 128 + ty * 4 + rr;
            if (b >= NGRAPH) continue;
#pragma unroll
            for (int ch = 0; ch < 2; ++ch) {
                int col = ct * 128 + ch * 64 + tx * 4;
                int o = col >> 5, L = col & 31;
                float4 v = make_float4(acc[rh * 4 + rr][ch * 4 + 0],
                                       acc[rh * 4 + rr][ch * 4 + 1],
                                       acc[rh * 4 + rr][ch * 4 + 2],
                                       acc[rh * 4 + rr][ch * 4 + 3]);
                *reinterpret_cast<float4*>(priors + (((size_t)b * 16 + o) * KP + i) * 32 + L) = v;
            }
        }
}

// ---------------- capsule-1 routing (per graph, all in LDS) ----------------
__global__ __launch_bounds__(256) void k_routing1(const float* __restrict__ priors_g,
                                                  float* __restrict__ v_out) {
    int b = blockIdx.x;
    __shared__ float P[16 * KP * 33];
    __shared__ float logits[16 * KP];
    __shared__ float c[16 * KP];
    __shared__ float s[16 * 32];
    __shared__ float v[16 * 32];
    __shared__ float scale[16];
    int t = threadIdx.x;
    const float* pg = priors_g + (size_t)b * (16 * KP * 32);
    for (int idx = t; idx < 16 * KP * 32; idx += 256)
        P[(idx >> 5) * 33 + (idx & 31)] = pg[idx];
    for (int idx = t; idx < 16 * KP; idx += 256) logits[idx] = 0.f;
    __syncthreads();
    for (int it = 0; it < 3; ++it) {
        if (t < KP) {
            float m = -1e30f;
            for (int o = 0; o < 16; ++o) m = fmaxf(m, logits[o * KP + t]);
            float sum = 0.f;
            for (int o = 0; o < 16; ++o) {
                float e = expf(logits[o * KP + t] - m);
                c[o * KP + t] = e;
                sum += e;
            }
            for (int o = 0; o < 16; ++o) c[o * KP + t] /= sum;
        }
        __syncthreads();
        for (int idx = t; idx < 16 * 32; idx += 256) {
            int o = idx >> 5, L = idx & 31;
            float acc = 0.f;
            for (int i = 0; i < KP; ++i) acc += c[o * KP + i] * P[(o * KP + i) * 33 + L];
            s[idx] = acc;
        }
        __syncthreads();
        if (t < 16) {
            float sq = 0.f;
            for (int L = 0; L < 32; ++L) sq += s[t * 32 + L] * s[t * 32 + L];
            scale[t] = (sq / (1.f + sq)) * (1.0f / sqrtf(sq + 1e-12f));
        }
        __syncthreads();
        for (int idx = t; idx < 16 * 32; idx += 256) v[idx] = s[idx] * scale[idx >> 5];
        __syncthreads();
        if (it < 2) {
            for (int idx = t; idx < 16 * KP; idx += 256) {
                int o = idx / KP, i = idx % KP;
                float acc = 0.f;
                for (int L = 0; L < 32; ++L) acc += P[(o * KP + i) * 33 + L] * v[o * 32 + L];
                logits[idx] += acc;
            }
            __syncthreads();
        }
    }
    for (int idx = t; idx < 16 * 32; idx += 256) v_out[(size_t)b * 512 + idx] = v[idx];
}

// ---------------- capsule-2 priors ----------------
__global__ __launch_bounds__(256) void k_priors2(const float* __restrict__ v1,
                                                 const float* __restrict__ Wc2,
                                                 float* __restrict__ priors2) {
    int b = blockIdx.x;
    __shared__ float ul[16 * 32];
    int t = threadIdx.x;
    for (int idx = t; idx < 512; idx += 256) ul[idx] = v1[(size_t)b * 512 + idx];
    __syncthreads();
    for (int idx = t; idx < NCLS * 16 * 16; idx += 256) {
        int L = idx & 15, i = (idx >> 4) & 15, o = idx >> 8;
        const float* wr = Wc2 + ((size_t)((o * 16 + i) * 16 + L)) * 32;
        const float* ur = &ul[i * 32];
        float acc = 0.f;
        for (int l = 0; l < 32; ++l) acc += wr[l] * ur[l];
        priors2[(size_t)b * (NCLS * 16 * 16) + idx] = acc;
    }
}

// ---------------- capsule-2 routing + final norms ----------------
__global__ __launch_bounds__(256) void k_routing2(const float* __restrict__ priors_g,
                                                  float* __restrict__ out) {
    int b = blockIdx.x;
    __shared__ float P[NCLS * 16 * 17];
    __shared__ float logits[NCLS * 16];
    __shared__ float c[NCLS * 16];
    __shared__ float s[NCLS * 16];
    __shared__ float v[NCLS * 16];
    __shared__ float scale[NCLS];
    int t = threadIdx.x;
    const float* pg = priors_g + (size_t)b * (NCLS * 16 * 16);
    for (int idx = t; idx < NCLS * 16 * 16; idx += 256)
        P[(idx >> 4) * 17 + (idx & 15)] = pg[idx];
    for (int idx = t; idx < NCLS * 16; idx += 256) logits[idx] = 0.f;
    __syncthreads();
    for (int it = 0; it < 3; ++it) {
        if (t < 16) {
            float m = -1e30f;
            for (int o = 0; o < NCLS; ++o) m = fmaxf(m, logits[o * 16 + t]);
            float sum = 0.f;
            for (int o = 0; o < NCLS; ++o) {
                float e = expf(logits[o * 16 + t] - m);
                c[o * 16 + t] = e;
                sum += e;
            }
            for (int o = 0; o < NCLS; ++o) c[o * 16 + t] /= sum;
        }
        __syncthreads();
        if (t < NCLS * 16) {
            int o = t >> 4, L = t & 15;
            float acc = 0.f;
            for (int i = 0; i < 16; ++i) acc += c[o * 16 + i] * P[(o * 16 + i) * 17 + L];
            s[t] = acc;
        }
        __syncthreads();
        if (t < NCLS) {
            float sq = 0.f;
            for (int L = 0; L < 16; ++L) sq += s[t * 16 + L] * s[t * 16 + L];
            scale[t] = (sq / (1.f + sq)) * (1.0f / sqrtf(sq + 1e-12f));
        }
        __syncthreads();
        if (t < NCLS * 16) v[t] = s[t] * scale[t >> 4];
        __syncthreads();
        if (it < 2) {
            if (t < NCLS * 16) {
                int o = t >> 4, i = t & 15;
                float acc = 0.f;
                for (int L = 0; L < 16; ++L) acc += P[(o * 16 + i) * 17 + L] * v[o * 16 + L];
                logits[t] += acc;
            }
            __syncthreads();
        }
    }
    if (t < NCLS) {
        float sq = 0.f;
        for (int L = 0; L < 16; ++L) sq += v[t * 16 + L] * v[t * 16 + L];
        out[(size_t)b * NCLS + t] = sqrtf(sq);
    }
}

extern "C" void kernel_launch(void* const* d_in, const int* in_sizes, int n_in,
                              void* d_out, int out_size, void* d_ws, size_t ws_size,
                              hipStream_t stream) {
    const float* x   = (const float*)d_in[0];
    const int*   ei  = (const int*)d_in[1];
    const float* W1  = (const float*)d_in[3];
    const float* b1  = (const float*)d_in[4];
    const float* W2  = (const float*)d_in[5];
    const float* b2  = (const float*)d_in[6];
    const float* W3  = (const float*)d_in[7];
    const float* b3  = (const float*)d_in[8];
    const float* Wc1 = (const float*)d_in[9];
    const float* Wc2 = (const float*)d_in[10];
    float* out = (float*)d_out;
    float* wsf = (float*)d_ws;

    const int* src = ei;
    const int* dst = ei + NEDGES;

    // ---- workspace layout (float-element offsets) ----
    float*    xc      = wsf;                        // 9,600,000
    float*    R       = wsf + 9600000;
    int*      totals  = (int*)R;                    // 196
    int*      bstart  = (int*)(R + 200);            // 197
    int*      cursor  = (int*)(R + 400);            // 196
    float*    dinv    = R + 600;                    // 100,000
    int*      offs    = (int*)(R + 100600);         // 100,001
    unsigned* csorted = (unsigned*)(R + 200608);    // 3,200,000 (dead after k_fill2)
    int*      csrc    = (int*)(R + 3400608);        // 3,200,000
    float*    h       = R + 6600608;                // 3,200,000
    // phase B: pooled aliases the dead csorted region
    float*    pooled  = R + 200608;                 // 2,400,000
    float*    pr1     = R + 9800608;                // 12,800,000
    float*    v1      = R + 22600608;               // 256,000
    float*    pr2     = R + 22856608;               // 1,280,000

    // ---- CSR build: bucketed two-level (coalesced writes) ----
    hipMemsetAsync(totals, 0, NB1 * sizeof(int), stream);
    k_hist1<<<NBLK1, 512, 0, stream>>>(src, dst, totals);
    k_scanb<<<1, 256, 0, stream>>>(totals, bstart, cursor, offs);
    k_place1<<<NBLK1, 512, 0, stream>>>(src, dst, cursor, csorted);
    k_fill2<<<NB1, 512, 0, stream>>>(bstart, csorted, csrc, offs, dinv);

    // ---- layer 1 ----
    k_matmul<<<(NNODES + 63) / 64, 256, 0, stream>>>(x, FIN, FIN, W1, dinv, h);
    k_gather<<<NNODES / 4, 256, 0, stream>>>(offs, csrc, dinv, h, b1, xc, 0);
    // ---- layer 2 ----
    k_matmul<<<(NNODES + 63) / 64, 256, 0, stream>>>(xc, 96, HID, W2, dinv, h);
    k_gather<<<NNODES / 4, 256, 0, stream>>>(offs, csrc, dinv, h, b2, xc, 32);
    // ---- layer 3 ----
    k_matmul<<<(NNODES + 63) / 64, 256, 0, stream>>>(xc + 32, 96, HID, W3, dinv, h);
    k_gather<<<NNODES / 4, 256, 0, stream>>>(offs, csrc, dinv, h, b3, xc, 64);

    // ---- sort-pool + capsules ----
    k_sortpool<<<NGRAPH, 256, 0, stream>>>(xc, pooled);
    k_priors1<<<KP * 8, 512, 0, stream>>>(pooled, Wc1, pr1);
    k_routing1<<<NGRAPH, 256, 0, stream>>>(pr1, v1);
    k_priors2<<<NGRAPH, 256, 0, stream>>>(v1, Wc2, pr2);
    k_routing2<<<NGRAPH, 256, 0, stream>>>(pr2, out);
}

// Round 8
// 394.508 us; speedup vs baseline: 11.1590x; 1.0563x over previous
//
#include <hip/hip_runtime.h>

#define NNODES 100000
#define NEDGES 3200000
#define NPG 200
#define NGRAPH 500
#define FIN 128
#define HID 32
#define KP 50
#define NCLS 10

#define NB1 196      // ceil(100000/512) dst-buckets
#define BSH 9
#define CHUNK 8192
#define NBLK1 391    // ceil(NEDGES/CHUNK)
#define CAP 17408    // per-bucket slot capacity (mean 16384 + 8 sigma)

// ---------------- level-1 place: LDS-binned partition, direct bucket reservation ----------------
__global__ __launch_bounds__(512) void k_place1(const int* __restrict__ src,
                                                const int* __restrict__ dst,
                                                int* __restrict__ cursor,
                                                unsigned* __restrict__ csorted) {
    __shared__ int hist[NB1];
    __shared__ int lstart[NB1];
    __shared__ int base[NB1];
    __shared__ int cnt2[NB1];
    __shared__ int sarr[256];
    __shared__ unsigned buf[CHUNK];
    __shared__ int dbuf[CHUNK];
    int t = threadIdx.x;
    for (int i = t; i < NB1; i += 512) { hist[i] = 0; cnt2[i] = 0; }
    __syncthreads();
    int eb = blockIdx.x * CHUNK;
    for (int i = 0; i < CHUNK / 512; ++i) {
        int e = eb + t + i * 512;
        if (e < NEDGES) {
            int s = src[e], d = dst[e];
            if (s != d) atomicAdd(&hist[d >> BSH], 1);
        }
    }
    __syncthreads();
    if (t < 256) sarr[t] = (t < NB1) ? hist[t] : 0;
    __syncthreads();
    for (int ofs = 1; ofs < 256; ofs <<= 1) {
        int add = (t < 256 && t >= ofs) ? sarr[t - ofs] : 0;
        __syncthreads();
        if (t < 256) sarr[t] += add;
        __syncthreads();
    }
    if (t < NB1) {
        lstart[t] = (t == 0) ? 0 : sarr[t - 1];
        base[t] = hist[t] ? (t * CAP + atomicAdd(&cursor[t], hist[t])) : 0;
    }
    __syncthreads();
    for (int i = 0; i < CHUNK / 512; ++i) {
        int e = eb + t + i * 512;
        if (e < NEDGES) {
            int s = src[e], d = dst[e];
            if (s != d) {
                int bk = d >> BSH;
                int pos = atomicAdd(&cnt2[bk], 1);
                int slot = lstart[bk] + pos;
                buf[slot] = ((unsigned)s << BSH) | (unsigned)(d & 511);
                dbuf[slot] = base[bk] + pos;
            }
        }
    }
    __syncthreads();
    int nval = sarr[NB1 - 1];
    for (int j = t; j < nval; j += 512) csorted[dbuf[j]] = buf[j];
}

// ---------------- level-2: per-bucket CSR finalize (+begend, +dinv) ----------------
__global__ __launch_bounds__(512) void k_fill2(const int* __restrict__ cursor,
                                               const unsigned* __restrict__ csorted,
                                               int* __restrict__ csrc,
                                               int2* __restrict__ begend,
                                               float* __restrict__ dinv) {
    __shared__ int cnt[512];
    __shared__ int loffs[512];
    __shared__ int cnt2[512];
    __shared__ int sarr[512];
    int b = blockIdx.x, t = threadIdx.x;
    cnt[t] = 0; cnt2[t] = 0;
    __syncthreads();
    int base = b * CAP;
    int m = cursor[b];
    for (int j = t; j < m; j += 512) atomicAdd(&cnt[csorted[base + j] & 511], 1);
    __syncthreads();
    sarr[t] = cnt[t];
    __syncthreads();
    for (int ofs = 1; ofs < 512; ofs <<= 1) {
        int add = (t >= ofs) ? sarr[t - ofs] : 0;
        __syncthreads();
        sarr[t] += add;
        __syncthreads();
    }
    loffs[t] = sarr[t] - cnt[t];  // exclusive
    __syncthreads();
    int n = b * 512 + t;
    if (n < NNODES) {
        int beg = base + loffs[t];
        begend[n] = make_int2(beg, beg + cnt[t]);
        dinv[n] = rsqrtf((float)cnt[t] + 1.0f);
    }
    for (int j = t; j < m; j += 512) {
        unsigned p = csorted[base + j];
        int d = p & 511;
        int pos = atomicAdd(&cnt2[d], 1);
        csrc[base + loffs[d] + pos] = (int)(p >> BSH);
    }
}

// ---------------- hw = (X @ W) * dinv : 64 rows/block, 8 rows/thread ----------------
__global__ __launch_bounds__(256) void k_matmul(const float* __restrict__ X, int ldx, int K,
                                                const float* __restrict__ W,
                                                const float* __restrict__ dinv,
                                                float* __restrict__ h) {
    __shared__ float Wl[FIN * HID];
    __shared__ float Xl[64 * FIN];
    int t = threadIdx.x;
    for (int idx = t; idx < K * HID; idx += 256) Wl[idx] = W[idx];
    int n0 = blockIdx.x * 64;
    int ng = 64 * K / 4;
    for (int idx = t; idx < ng; idx += 256) {
        int r = (idx * 4) / K, c = (idx * 4) % K;
        float4 v = make_float4(0.f, 0.f, 0.f, 0.f);
        if (n0 + r < NNODES)
            v = *reinterpret_cast<const float4*>(X + (size_t)(n0 + r) * ldx + c);
        *reinterpret_cast<float4*>(&Xl[r * K + c]) = v;
    }
    __syncthreads();
    int j = t & 31, g = t >> 5;
    const float* xr = &Xl[(g * 8) * K];
    float a0 = 0, a1 = 0, a2 = 0, a3 = 0, a4 = 0, a5 = 0, a6 = 0, a7 = 0;
    for (int k = 0; k < K; ++k) {
        float w = Wl[k * HID + j];
        a0 += w * xr[0 * K + k];
        a1 += w * xr[1 * K + k];
        a2 += w * xr[2 * K + k];
        a3 += w * xr[3 * K + k];
        a4 += w * xr[4 * K + k];
        a5 += w * xr[5 * K + k];
        a6 += w * xr[6 * K + k];
        a7 += w * xr[7 * K + k];
    }
    int r0 = n0 + g * 8;
    float av[8] = {a0, a1, a2, a3, a4, a5, a6, a7};
    for (int q = 0; q < 8; ++q)
        if (r0 + q < NNODES) h[(size_t)(r0 + q) * HID + j] = av[q] * dinv[r0 + q];
}

// ---------------- gather: 2 nodes/wave, 8-deep unroll (64 lines in flight/wave) ----------------
__global__ __launch_bounds__(256) void k_gather(const int2* __restrict__ begend,
                                                const int* __restrict__ csrc,
                                                const float* __restrict__ dinv,
                                                const float* __restrict__ hw,
                                                const float* __restrict__ bias,
                                                float* __restrict__ xc, int coloff) {
    int t = threadIdx.x;
    int wv = t >> 6;
    int lane = t & 63;
    int nh = lane >> 5;    // node half within wave
    int sub = lane & 31;
    int g = sub >> 3;      // edge slot 0..3
    int q = sub & 7;       // channel quad 0..7
    int n = blockIdx.x * 8 + wv * 2 + nh;
    int2 be = begend[n];
    int beg = be.x, end = be.y, last = end - 1;
    float4 acc = make_float4(0.f, 0.f, 0.f, 0.f);
    for (int e0 = beg + g; e0 < end; e0 += 32) {
#pragma unroll
        for (int j = 0; j < 8; ++j) {
            int e = e0 + 4 * j;
            float mk = (e <= last) ? 1.f : 0.f;
            int s = csrc[min(e, last)];
            float4 hv = *reinterpret_cast<const float4*>(hw + (size_t)s * HID + q * 4);
            acc.x += mk * hv.x; acc.y += mk * hv.y; acc.z += mk * hv.z; acc.w += mk * hv.w;
        }
    }
    // reduce over the 4 edge slots (within each 32-lane node group)
    for (int m = 8; m <= 16; m <<= 1) {
        acc.x += __shfl_xor(acc.x, m, 64);
        acc.y += __shfl_xor(acc.y, m, 64);
        acc.z += __shfl_xor(acc.z, m, 64);
        acc.w += __shfl_xor(acc.w, m, 64);
    }
    if (g == 0) {
        float di = dinv[n];
        float4 hv = *reinterpret_cast<const float4*>(hw + (size_t)n * HID + q * 4);
        float4 bv = *reinterpret_cast<const float4*>(bias + q * 4);
        float4 v;
        v.x = tanhf(di * (acc.x + hv.x) + bv.x);
        v.y = tanhf(di * (acc.y + hv.y) + bv.y);
        v.z = tanhf(di * (acc.z + hv.z) + bv.z);
        v.w = tanhf(di * (acc.w + hv.w) + bv.w);
        *reinterpret_cast<float4*>(xc + (size_t)n * 96 + coloff + q * 4) = v;
    }
}

// ---------------- stable top-50 sort-pool per graph ----------------
__global__ __launch_bounds__(256) void k_sortpool(const float* __restrict__ xc,
                                                  float* __restrict__ pooled) {
    int g = blockIdx.x;
    __shared__ float vals[NPG];
    __shared__ int sel[KP];
    int t = threadIdx.x;
    if (t < NPG) vals[t] = xc[((size_t)g * NPG + t) * 96 + 95];
    __syncthreads();
    if (t < NPG) {
        float v = vals[t];
        int r = 0;
        for (int k = 0; k < NPG; ++k) {
            float vk = vals[k];
            r += (vk > v) || (vk == v && k < t);
        }
        if (r < KP) sel[r] = t;
    }
    __syncthreads();
    for (int idx = t; idx < KP * 24; idx += 256) {
        int r = idx / 24, c4 = (idx % 24) * 4;
        *reinterpret_cast<float4*>(pooled + (size_t)g * KP * 96 + r * 96 + c4) =
            *reinterpret_cast<const float4*>(xc + ((size_t)g * NPG + sel[r]) * 96 + c4);
    }
}

// ---------------- capsule-1 priors: 256x128 tile, 8x8/thread, K-split LDS ----------------
__global__ __launch_bounds__(512) void k_priors1(const float* __restrict__ pooled,
                                                 const float* __restrict__ Wc1,
                                                 float* __restrict__ priors) {
    int bid = blockIdx.x;
    int ct = bid & 3;
    int bt = (bid >> 2) & 1;
    int i = bid >> 3;
    __shared__ float As[48 * 256];
    __shared__ float Bs[48 * 128];
    int t = threadIdx.x;
    int tx = t & 15, ty = t >> 4;
    float acc[8][8];
#pragma unroll
    for (int r = 0; r < 8; ++r)
#pragma unroll
        for (int c = 0; c < 8; ++c) acc[r][c] = 0.f;

    for (int kh = 0; kh < 2; ++kh) {
        int kbase = kh * 48;
        __syncthreads();
        for (int idx = t; idx < 256 * 12; idx += 512) {
            int r = idx / 12, c4 = (idx % 12) * 4;
            int b = bt * 256 + r;
            float4 v = make_float4(0.f, 0.f, 0.f, 0.f);
            if (b < NGRAPH)
                v = *reinterpret_cast<const float4*>(pooled + ((size_t)b * KP + i) * 96 + kbase + c4);
            float vv[4] = {v.x, v.y, v.z, v.w};
#pragma unroll
            for (int j = 0; j < 4; ++j) {
                int k = c4 + j;
                int gp = (r >> 2) ^ ((k >> 2) & 31);
                As[k * 256 + gp * 4 + (r & 3)] = vv[j];
            }
        }
        for (int idx = t; idx < 128 * 12; idx += 512) {
            int c = idx / 12, c4 = (idx % 12) * 4;
            int col = ct * 128 + c;
            const float* wr = Wc1 + (((size_t)(col >> 5) * KP + i) * 32 + (col & 31)) * 96;
            float4 v = *reinterpret_cast<const float4*>(wr + kbase + c4);
            float vv[4] = {v.x, v.y, v.z, v.w};
#pragma unroll
            for (int j = 0; j < 4; ++j) {
                int k = c4 + j;
                int gp = (c >> 2) ^ ((k >> 2) & 31);
                Bs[k * 128 + gp * 4 + (c & 3)] = vv[j];
            }
        }
        __syncthreads();
        for (int k = 0; k < 48; ++k) {
            int key = (k >> 2) & 31;
            float4 a0 = *reinterpret_cast<const float4*>(&As[k * 256 + 4 * (ty ^ key)]);
            float4 a1 = *reinterpret_cast<const float4*>(&As[k * 256 + 4 * ((32 + ty) ^ key)]);
            float4 b0 = *reinterpret_cast<const float4*>(&Bs[k * 128 + 4 * (tx ^ key)]);
            float4 b1 = *reinterpret_cast<const float4*>(&Bs[k * 128 + 4 * ((16 + tx) ^ key)]);
            float a[8] = {a0.x, a0.y, a0.z, a0.w, a1.x, a1.y, a1.z, a1.w};
            float bb[8] = {b0.x, b0.y, b0.z, b0.w, b1.x, b1.y, b1.z, b1.w};
#pragma unroll
            for (int r = 0; r < 8; ++r)
#pragma unroll
                for (int c = 0; c < 8; ++c) acc[r][c] += a[r] * bb[c];
        }
    }
#pragma unroll
    for (int rh = 0; rh < 2; ++rh)
#pragma unroll
        for (int rr = 0; rr < 4; ++rr) {
            int b = bt * 256 + rh * 128 + ty * 4 + rr;
            if (b >= NGRAPH) continue;
#pragma unroll
            for (int ch = 0; ch < 2; ++ch) {
                int col = ct * 128 + ch * 64 + tx * 4;
                int o = col >> 5, L = col & 31;
                float4 v = make_float4(acc[rh * 4 + rr][ch * 4 + 0],
                                       acc[rh * 4 + rr][ch * 4 + 1],
                                       acc[rh * 4 + rr][ch * 4 + 2],
                                       acc[rh * 4 + rr][ch * 4 + 3]);
                *reinterpret_cast<float4*>(priors + (((size_t)b * 16 + o) * KP + i) * 32 + L) = v;
            }
        }
}

// ---------------- capsule-1 routing (per graph, all in LDS) ----------------
__global__ __launch_bounds__(256) void k_routing1(const float* __restrict__ priors_g,
                                                  float* __restrict__ v_out) {
    int b = blockIdx.x;
    __shared__ float P[16 * KP * 33];
    __shared__ float logits[16 * KP];
    __shared__ float c[16 * KP];
    __shared__ float s[16 * 32];
    __shared__ float v[16 * 32];
    __shared__ float scale[16];
    int t = threadIdx.x;
    const float* pg = priors_g + (size_t)b * (16 * KP * 32);
    for (int idx = t; idx < 16 * KP * 32; idx += 256)
        P[(idx >> 5) * 33 + (idx & 31)] = pg[idx];
    for (int idx = t; idx < 16 * KP; idx += 256) logits[idx] = 0.f;
    __syncthreads();
    for (int it = 0; it < 3; ++it) {
        if (t < KP) {
            float m = -1e30f;
            for (int o = 0; o < 16; ++o) m = fmaxf(m, logits[o * KP + t]);
            float sum = 0.f;
            for (int o = 0; o < 16; ++o) {
                float e = expf(logits[o * KP + t] - m);
                c[o * KP + t] = e;
                sum += e;
            }
            for (int o = 0; o < 16; ++o) c[o * KP + t] /= sum;
        }
        __syncthreads();
        for (int idx = t; idx < 16 * 32; idx += 256) {
            int o = idx >> 5, L = idx & 31;
            float acc = 0.f;
            for (int i = 0; i < KP; ++i) acc += c[o * KP + i] * P[(o * KP + i) * 33 + L];
            s[idx] = acc;
        }
        __syncthreads();
        if (t < 16) {
            float sq = 0.f;
            for (int L = 0; L < 32; ++L) sq += s[t * 32 + L] * s[t * 32 + L];
            scale[t] = (sq / (1.f + sq)) * (1.0f / sqrtf(sq + 1e-12f));
        }
        __syncthreads();
        for (int idx = t; idx < 16 * 32; idx += 256) v[idx] = s[idx] * scale[idx >> 5];
        __syncthreads();
        if (it < 2) {
            for (int idx = t; idx < 16 * KP; idx += 256) {
                int o = idx / KP, i = idx % KP;
                float acc = 0.f;
                for (int L = 0; L < 32; ++L) acc += P[(o * KP + i) * 33 + L] * v[o * 32 + L];
                logits[idx] += acc;
            }
            __syncthreads();
        }
    }
    for (int idx = t; idx < 16 * 32; idx += 256) v_out[(size_t)b * 512 + idx] = v[idx];
}

// ---------------- capsule-2 priors ----------------
__global__ __launch_bounds__(256) void k_priors2(const float* __restrict__ v1,
                                                 const float* __restrict__ Wc2,
                                                 float* __restrict__ priors2) {
    int b = blockIdx.x;
    __shared__ float ul[16 * 32];
    int t = threadIdx.x;
    for (int idx = t; idx < 512; idx += 256) ul[idx] = v1[(size_t)b * 512 + idx];
    __syncthreads();
    for (int idx = t; idx < NCLS * 16 * 16; idx += 256) {
        int L = idx & 15, i = (idx >> 4) & 15, o = idx >> 8;
        const float* wr = Wc2 + ((size_t)((o * 16 + i) * 16 + L)) * 32;
        const float* ur = &ul[i * 32];
        float acc = 0.f;
        for (int l = 0; l < 32; ++l) acc += wr[l] * ur[l];
        priors2[(size_t)b * (NCLS * 16 * 16) + idx] = acc;
    }
}

// ---------------- capsule-2 routing + final norms ----------------
__global__ __launch_bounds__(256) void k_routing2(const float* __restrict__ priors_g,
                                                  float* __restrict__ out) {
    int b = blockIdx.x;
    __shared__ float P[NCLS * 16 * 17];
    __shared__ float logits[NCLS * 16];
    __shared__ float c[NCLS * 16];
    __shared__ float s[NCLS * 16];
    __shared__ float v[NCLS * 16];
    __shared__ float scale[NCLS];
    int t = threadIdx.x;
    const float* pg = priors_g + (size_t)b * (NCLS * 16 * 16);
    for (int idx = t; idx < NCLS * 16 * 16; idx += 256)
        P[(idx >> 4) * 17 + (idx & 15)] = pg[idx];
    for (int idx = t; idx < NCLS * 16; idx += 256) logits[idx] = 0.f;
    __syncthreads();
    for (int it = 0; it < 3; ++it) {
        if (t < 16) {
            float m = -1e30f;
            for (int o = 0; o < NCLS; ++o) m = fmaxf(m, logits[o * 16 + t]);
            float sum = 0.f;
            for (int o = 0; o < NCLS; ++o) {
                float e = expf(logits[o * 16 + t] - m);
                c[o * 16 + t] = e;
                sum += e;
            }
            for (int o = 0; o < NCLS; ++o) c[o * 16 + t] /= sum;
        }
        __syncthreads();
        if (t < NCLS * 16) {
            int o = t >> 4, L = t & 15;
            float acc = 0.f;
            for (int i = 0; i < 16; ++i) acc += c[o * 16 + i] * P[(o * 16 + i) * 17 + L];
            s[t] = acc;
        }
        __syncthreads();
        if (t < NCLS) {
            float sq = 0.f;
            for (int L = 0; L < 16; ++L) sq += s[t * 16 + L] * s[t * 16 + L];
            scale[t] = (sq / (1.f + sq)) * (1.0f / sqrtf(sq + 1e-12f));
        }
        __syncthreads();
        if (t < NCLS * 16) v[t] = s[t] * scale[t >> 4];
        __syncthreads();
        if (it < 2) {
            if (t < NCLS * 16) {
                int o = t >> 4, i = t & 15;
                float acc = 0.f;
                for (int L = 0; L < 16; ++L) acc += P[(o * 16 + i) * 17 + L] * v[o * 16 + L];
                logits[t] += acc;
            }
            __syncthreads();
        }
    }
    if (t < NCLS) {
        float sq = 0.f;
        for (int L = 0; L < 16; ++L) sq += v[t * 16 + L] * v[t * 16 + L];
        out[(size_t)b * NCLS + t] = sqrtf(sq);
    }
}

extern "C" void kernel_launch(void* const* d_in, const int* in_sizes, int n_in,
                              void* d_out, int out_size, void* d_ws, size_t ws_size,
                              hipStream_t stream) {
    const float* x   = (const float*)d_in[0];
    const int*   ei  = (const int*)d_in[1];
    const float* W1  = (const float*)d_in[3];
    const float* b1  = (const float*)d_in[4];
    const float* W2  = (const float*)d_in[5];
    const float* b2  = (const float*)d_in[6];
    const float* W3  = (const float*)d_in[7];
    const float* b3  = (const float*)d_in[8];
    const float* Wc1 = (const float*)d_in[9];
    const float* Wc2 = (const float*)d_in[10];
    float* out = (float*)d_out;
    float* wsf = (float*)d_ws;

    const int* src = ei;
    const int* dst = ei + NEDGES;

    // ---- workspace layout (float-element offsets) ----
    float* xc = wsf;                                // 9,600,000
    float* R  = wsf + 9600000;
    int*   cursor  = (int*)R;                       // 196 (pad to 256)
    float* dinv    = R + 256;                       // 100,000
    int2*  begend  = (int2*)(R + 100256);           // 100,000 int2 = 200,000
    float* A       = R + 300256;                    // shared region: csorted | h | pooled
    unsigned* csorted = (unsigned*)A;               // NB1*CAP = 3,411,968
    float* h       = A;                             // 3,200,000 (after fill2, csorted dead)
    float* pooled  = A;                             // 2,400,000 (after gather3, h dead)
    int*   csrc    = (int*)(R + 3712224);           // 3,411,968 (bucket-strided)
    float* pr1     = R + 7124192;                   // 12,800,000
    float* v1      = R + 19924192;                  // 256,000
    float* pr2     = R + 20180192;                  // 1,280,000  (R ends ~21.5M floats)

    // ---- CSR build: single-pass bucketed placement (fixed capacity) ----
    hipMemsetAsync(cursor, 0, 256 * sizeof(int), stream);
    k_place1<<<NBLK1, 512, 0, stream>>>(src, dst, cursor, csorted);
    k_fill2<<<NB1, 512, 0, stream>>>(cursor, csorted, csrc, begend, dinv);

    // ---- layer 1 ----
    k_matmul<<<(NNODES + 63) / 64, 256, 0, stream>>>(x, FIN, FIN, W1, dinv, h);
    k_gather<<<NNODES / 8, 256, 0, stream>>>(begend, csrc, dinv, h, b1, xc, 0);
    // ---- layer 2 ----
    k_matmul<<<(NNODES + 63) / 64, 256, 0, stream>>>(xc, 96, HID, W2, dinv, h);
    k_gather<<<NNODES / 8, 256, 0, stream>>>(begend, csrc, dinv, h, b2, xc, 32);
    // ---- layer 3 ----
    k_matmul<<<(NNODES + 63) / 64, 256, 0, stream>>>(xc + 32, 96, HID, W3, dinv, h);
    k_gather<<<NNODES / 8, 256, 0, stream>>>(begend, csrc, dinv, h, b3, xc, 64);

    // ---- sort-pool + capsules ----
    k_sortpool<<<NGRAPH, 256, 0, stream>>>(xc, pooled);
    k_priors1<<<KP * 8, 512, 0, stream>>>(pooled, Wc1, pr1);
    k_routing1<<<NGRAPH, 256, 0, stream>>>(pr1, v1);
    k_priors2<<<NGRAPH, 256, 0, stream>>>(v1, Wc2, pr2);
    k_routing2<<<NGRAPH, 256, 0, stream>>>(pr2, out);
}